// Round 10
// baseline (1409.819 us; speedup 1.0000x reference)
//
#include <hip/hip_runtime.h>

// HNN structure embed (N=3, HID=1024, bs=32768).
// GEMMs: bf16 MFMA 16x16x32, 256x256x64 tiles, 512 thr = 8 waves (2Mx4N,
// 128x64/wave, acc[8][4]=128 AGPR), 2-slot LDS ring (128 KB) with counted
// vmcnt(8) prefetch. R9 register discipline carried over: one A-fragment at
// a time, voff[4] shared staging offsets, full-unroll epilogue with
// sched_barrier(0) per m-chunk (keeps acc in AGPRs, caps live range).
// 8 waves in one block = 2 waves/SIMD co-resident by construction.
// Per-row 3x3 algebra in f32. dHdp == q_dot (exact). V layer-3 fwd skipped.

#define HID 1024
#define BS  32768

typedef __attribute__((ext_vector_type(8))) short short8;
typedef __attribute__((ext_vector_type(4))) float f32x4;
typedef __attribute__((ext_vector_type(8))) unsigned short ushort8v;
typedef __attribute__((ext_vector_type(4))) unsigned short ushort4v;

typedef __attribute__((address_space(1))) const char gconst_char;
typedef __attribute__((address_space(3))) char lds_char;

__device__ __forceinline__ unsigned short f2bf(float f) {
  unsigned int u = __builtin_bit_cast(unsigned int, f);
  u += 0x7fffu + ((u >> 16) & 1u);   // RNE
  return (unsigned short)(u >> 16);
}
__device__ __forceinline__ float bf2f(unsigned short s) {
  unsigned int u = ((unsigned int)s) << 16;
  return __builtin_bit_cast(float, u);
}
__device__ __forceinline__ float tanh_fast(float x) {
  float e = __builtin_amdgcn_exp2f(x * 2.885390081777927f); // e^(2x)
  return 1.f - 2.f * __builtin_amdgcn_rcpf(e + 1.f);
}

// ---------------- weight packing: pT[n][k]=bf16(W[k][n]); pC[n][k]=bf16(W[n][k])
__global__ __launch_bounds__(256) void pack_w(const float* __restrict__ W,
                                              unsigned short* __restrict__ pT,
                                              unsigned short* __restrict__ pC) {
  __shared__ float tile[64][65];
  int b = blockIdx.x;
  int k0 = (b >> 4) << 6;
  int n0 = (b & 15) << 6;
  int t = threadIdx.x;
  for (int i = 0; i < 16; ++i) {
    int idx = i * 256 + t;
    int r = idx >> 6, c = idx & 63;
    tile[r][c] = W[(size_t)(k0 + r) * HID + n0 + c];
  }
  if (pC) {
    for (int i = 0; i < 16; ++i) {
      int idx = i * 256 + t;
      int r = idx >> 6, c = idx & 63;
      pC[(size_t)(n0 + r) * HID + k0 + c] = f2bf(W[(size_t)(n0 + r) * HID + k0 + c]);
    }
  }
  __syncthreads();
  for (int i = 0; i < 16; ++i) {
    int idx = i * 256 + t;
    int n = idx >> 6, k = idx & 63;
    pT[(size_t)(n0 + n) * HID + k0 + k] = f2bf(tile[k][n]);
  }
}

// ---------------- big GEMM: C[m][n] = epi( sum_k A[m][k]*Bp[n][k] )
// 256x256 tile, BK=64, 512 threads = 8 waves (2M x 4N), 128x64 per wave.
// EPI 0: tanh(acc + bias[col])
// EPI 1: acc * bf2f(aux[row][col])                      (aux = d2 = 1-h2^2)
// EPI 2: acc * (1 - tanh(x6[row]@W1[:,col] + b1[col])^2)  (recompute d1)
template<int EPI>
__global__ __launch_bounds__(512) void gemm_bf16(
    const unsigned short* __restrict__ A,
    const unsigned short* __restrict__ Bp,
    unsigned short* __restrict__ C,
    const float* __restrict__ bias,
    const unsigned short* __restrict__ aux,
    const float* __restrict__ xall,
    const float* __restrict__ W1,
    const float* __restrict__ b1)
{
  __shared__ __align__(1024) char lds[131072];   // 2 x (A 32K + B 32K)
  const int t = threadIdx.x;
  const int w = t >> 6, l = t & 63;
  // bijective XCD swizzle: 512 blocks, 8 XCDs, 64 wgs each; nt fastest so
  // one A-panel's 4 column-blocks are consecutive within an XCD.
  int bid = (int)blockIdx.x;
  int wg  = (bid & 7) * 64 + (bid >> 3);
  const int nt = wg & 3, mt = wg >> 2;
  const int r0 = mt << 8, n0 = nt << 8;
  const int wr = w >> 2, wc = w & 3;      // wave tile: rows wr*128, cols wc*64

  f32x4 acc[8][4] = {};

  // staging offsets: A-tile 256 rows x 128 B = 32 KB = 32 chunks of 1 KB;
  // chunk c = i*8 + w; per-lane global offset shared by A and B.
  int voff[4];
  #pragma unroll
  for (int i = 0; i < 4; ++i) {
    int o   = (((i << 3) + w) << 10) + (l << 4);
    int row = o >> 7;
    voff[i] = (row << 11) + ((o & 127) ^ ((row & 7) << 4));   // inv swizzle on SOURCE
  }
  const char* Abase = (const char*)A  + ((size_t)r0 << 11);
  const char* Bbase = (const char*)Bp + ((size_t)n0 << 11);

  // stage K-tile kt into slot `buf`; uniform part (kt*128) stays scalar
  auto STAGE = [&](int buf, int kt) {
    char* Ad = lds + (buf << 16);
    char* Bd = Ad + 32768;
    const char* Ak = Abase + kt * 128;
    const char* Bk = Bbase + kt * 128;
    #pragma unroll
    for (int i = 0; i < 4; ++i) {
      __builtin_amdgcn_global_load_lds((gconst_char*)(Ak + voff[i]), (lds_char*)(Ad + (((i << 3) + w) << 10)), 16, 0, 0);
      __builtin_amdgcn_global_load_lds((gconst_char*)(Bk + voff[i]), (lds_char*)(Bd + (((i << 3) + w) << 10)), 16, 0, 0);
    }
  };

  auto COMPUTE = [&](int buf) {
    const char* As = lds + (buf << 16);
    const char* Bs = As + 32768;
    #pragma unroll
    for (int kk = 0; kk < 2; ++kk) {
      short8 bfr[4];
      #pragma unroll
      for (int n = 0; n < 4; ++n) {
        int col = (wc << 6) + (n << 4) + (l & 15);
        int off = (col << 7) + ((l >> 4) << 4) + (kk << 6);
        off ^= ((col & 7) << 4);
        bfr[n] = *(const short8*)(Bs + off);
      }
      #pragma unroll
      for (int m = 0; m < 8; ++m) {
        int row = (wr << 7) + (m << 4) + (l & 15);
        int off = (row << 7) + ((l >> 4) << 4) + (kk << 6);
        off ^= ((row & 7) << 4);
        short8 af = *(const short8*)(As + off);
        #pragma unroll
        for (int n = 0; n < 4; ++n) {
          acc[m][n] = __builtin_amdgcn_mfma_f32_16x16x32_bf16(af, bfr[n], acc[m][n], 0, 0, 0);
        }
      }
    }
  };

  // prologue: stage tile 0
  STAGE(0, 0);

  int cur = 0;
  #pragma unroll 1
  for (int kt = 0; kt < 16; ++kt) {
    if (kt < 15) {
      STAGE(cur ^ 1, kt + 1);                             // prefetch kt+1 (8 loads)
      asm volatile("s_waitcnt vmcnt(8)" ::: "memory");    // cur landed; next in flight
    } else {
      asm volatile("s_waitcnt vmcnt(0)" ::: "memory");    // tail drain
    }
    __builtin_amdgcn_s_barrier();
    COMPUTE(cur);
    __builtin_amdgcn_s_barrier();    // readers of cur done before it is overwritten
    cur ^= 1;
  }

  // epilogue: FULL unroll (compile-time acc indices -> AGPR, no scratch);
  // sched_barrier(0) after each m-chunk caps the accvgpr-read live range.
  // C-tile 256 rows x 512 B = 128 KB staged in LDS, then coalesced store.
  char* Cs = lds;
  #pragma unroll
  for (int n = 0; n < 4; ++n) {
    const int colL = (wc << 6) + (n << 4) + (l & 15);
    const int gcol = n0 + colL;
    float bval = 0.f;
    float w1c[6];
    if (EPI == 0) bval = bias[gcol];
    if (EPI == 2) {
      bval = b1[gcol];
      #pragma unroll
      for (int k2 = 0; k2 < 6; ++k2) w1c[k2] = W1[k2 * HID + gcol];
    }
    #pragma unroll
    for (int m = 0; m < 8; ++m) {
      #pragma unroll
      for (int r = 0; r < 4; ++r) {
        const int rowL = (wr << 7) + (m << 4) + ((l >> 4) << 2) + r;
        float v = acc[m][n][r];
        if (EPI == 0) {
          v = tanh_fast(v + bval);
        } else if (EPI == 1) {
          v *= bf2f(aux[((size_t)(r0 + rowL) << 10) + gcol]);
        } else {
          const float* xr = xall + (size_t)(r0 + rowL) * 10;
          float z = bval;
          #pragma unroll
          for (int k2 = 0; k2 < 6; ++k2) z += xr[k2] * w1c[k2];
          float th = tanh_fast(z);
          v *= (1.f - th * th);
        }
        int so = (rowL << 9) + (((colL << 1) ^ ((rowL & 31) << 4)));
        *(unsigned short*)(Cs + so) = f2bf(v);
      }
      __builtin_amdgcn_sched_barrier(0);   // cap live acc reads per chunk
    }
  }
  __syncthreads();
  #pragma unroll
  for (int j = 0; j < 16; ++j) {
    int o    = (j << 13) + (t << 4);
    int rowL = o >> 9;
    int ir   = o & 511;
    uint4 v = *(const uint4*)(Cs + ((rowL << 9) + (ir ^ ((rowL & 31) << 4))));
    *(uint4*)(C + ((size_t)(r0 + rowL) << 10) + n0 + (ir >> 1)) = v;
  }
}

// ---------------- layer-1 forward: out = tanh(x6 @ W1 + b1), bf16
__global__ __launch_bounds__(256) void l1fwd(const float* __restrict__ x,
                                             const float* __restrict__ W1,
                                             const float* __restrict__ b1,
                                             unsigned short* __restrict__ out) {
  int idx = blockIdx.x * 256 + threadIdx.x;
  int r = idx >> 7;
  int n8 = (idx & 127) << 3;
  const float* xr = x + (size_t)r * 10;
  float xs[6];
  #pragma unroll
  for (int k = 0; k < 6; ++k) xs[k] = xr[k];
  float4 bb0 = *(const float4*)(b1 + n8), bb1 = *(const float4*)(b1 + n8 + 4);
  float z[8] = {bb0.x, bb0.y, bb0.z, bb0.w, bb1.x, bb1.y, bb1.z, bb1.w};
  #pragma unroll
  for (int k = 0; k < 6; ++k) {
    const float* wrow = W1 + (size_t)k * HID + n8;
    float4 wa = *(const float4*)wrow, wb = *(const float4*)(wrow + 4);
    z[0] += xs[k] * wa.x; z[1] += xs[k] * wa.y; z[2] += xs[k] * wa.z; z[3] += xs[k] * wa.w;
    z[4] += xs[k] * wb.x; z[5] += xs[k] * wb.y; z[6] += xs[k] * wb.z; z[7] += xs[k] * wb.w;
  }
  ushort8v o;
  #pragma unroll
  for (int j = 0; j < 8; ++j) o[j] = f2bf(tanh_fast(z[j]));
  *(ushort8v*)(out + (size_t)r * HID + n8) = o;
}

// ---------------- JVP layer-1: th1 = (tang @ W1) * (1 - tanh(x@W1+b1)^2)
__global__ __launch_bounds__(256) void l1t(const float* __restrict__ x,
                                           const float* __restrict__ outbuf, // tangent in cols 0..5
                                           const float* __restrict__ W1,
                                           const float* __restrict__ b1,
                                           unsigned short* __restrict__ P) {
  int idx = blockIdx.x * 256 + threadIdx.x;
  int r = idx >> 7;
  int n8 = (idx & 127) << 3;
  const float* xr = x + (size_t)r * 10;
  const float* tr = outbuf + (size_t)r * 10;
  float xs[6], ts[6];
  #pragma unroll
  for (int k = 0; k < 6; ++k) { xs[k] = xr[k]; ts[k] = tr[k]; }
  float4 bb0 = *(const float4*)(b1 + n8), bb1 = *(const float4*)(b1 + n8 + 4);
  float z[8] = {bb0.x, bb0.y, bb0.z, bb0.w, bb1.x, bb1.y, bb1.z, bb1.w};
  float tz[8] = {};
  #pragma unroll
  for (int k = 0; k < 6; ++k) {
    const float* wrow = W1 + (size_t)k * HID + n8;
    float4 wa = *(const float4*)wrow, wb = *(const float4*)(wrow + 4);
    z[0] += xs[k] * wa.x;  z[1] += xs[k] * wa.y;  z[2] += xs[k] * wa.z;  z[3] += xs[k] * wa.w;
    z[4] += xs[k] * wb.x;  z[5] += xs[k] * wb.y;  z[6] += xs[k] * wb.z;  z[7] += xs[k] * wb.w;
    tz[0] += ts[k] * wa.x; tz[1] += ts[k] * wa.y; tz[2] += ts[k] * wa.z; tz[3] += ts[k] * wa.w;
    tz[4] += ts[k] * wb.x; tz[5] += ts[k] * wb.y; tz[6] += ts[k] * wb.z; tz[7] += ts[k] * wb.w;
  }
  ushort8v o;
  #pragma unroll
  for (int j = 0; j < 8; ++j) {
    float th = tanh_fast(z[j]);
    o[j] = f2bf(tz[j] * (1.f - th * th));
  }
  *(ushort8v*)(P + (size_t)r * HID + n8) = o;
}

// ---------------- g2 = (gL @ MW3^T) * d2, bf16  (K = 9)
__global__ __launch_bounds__(256) void k9bwd(const float* __restrict__ sGL,
                                             const float* __restrict__ MW3, // [1024][9]
                                             const unsigned short* __restrict__ d2,
                                             unsigned short* __restrict__ outp) {
  int idx = blockIdx.x * 256 + threadIdx.x;
  int r = idx >> 7;
  int n8 = (idx & 127) << 3;
  const float* g = sGL + (size_t)r * 9;
  float gl[9];
  #pragma unroll
  for (int j = 0; j < 9; ++j) gl[j] = g[j];
  ushort8v dv = *(const ushort8v*)(d2 + (size_t)r * HID + n8);
  ushort8v o;
  #pragma unroll
  for (int j = 0; j < 8; ++j) {
    const float* wr = MW3 + (size_t)(n8 + j) * 9;
    float s = 0.f;
    #pragma unroll
    for (int jj = 0; jj < 9; ++jj) s += gl[jj] * wr[jj];
    o[j] = f2bf(s * bf2f(dv[j]));
  }
  *(ushort8v*)(outp + (size_t)r * HID + n8) = o;
}

// ---------------- in-place maps
__global__ __launch_bounds__(256) void mapQ(unsigned short* __restrict__ Q) {
  size_t idx = (size_t)(blockIdx.x * 256 + threadIdx.x) * 8;
  ushort8v v = *(ushort8v*)(Q + idx);
  #pragma unroll
  for (int j = 0; j < 8; ++j) { float f = bf2f(v[j]); v[j] = f2bf(1.f - f * f); }
  *(ushort8v*)(Q + idx) = v;
}
__global__ __launch_bounds__(256) void mapV(unsigned short* __restrict__ Rb,
                                            const float* __restrict__ VW3) {
  int idx = blockIdx.x * 256 + threadIdx.x;
  int r = idx >> 7;
  int n8 = (idx & 127) << 3;
  ushort8v v = *(ushort8v*)(Rb + (size_t)r * HID + n8);
  float4 w0 = *(const float4*)(VW3 + n8), w1 = *(const float4*)(VW3 + n8 + 4);
  float wv[8] = {w0.x, w0.y, w0.z, w0.w, w1.x, w1.y, w1.z, w1.w};
  #pragma unroll
  for (int j = 0; j < 8; ++j) { float f = bf2f(v[j]); v[j] = f2bf(wv[j] * (1.f - f * f)); }
  *(ushort8v*)(Rb + (size_t)r * HID + n8) = v;
}

// ---------------- skinny reductions (wave per row)
template<bool BIAS>
__global__ __launch_bounds__(256) void skinny9(const unsigned short* __restrict__ A,
                                               const float* __restrict__ W,  // [1024][9]
                                               const float* __restrict__ bias,
                                               float* __restrict__ out) {
  int wid = blockIdx.x * 4 + (threadIdx.x >> 6);
  int l = threadIdx.x & 63;
  const unsigned short* ar = A + (size_t)wid * HID;
  float acc[9] = {};
  for (int i = 0; i < 16; ++i) {
    int k = i * 64 + l;
    float a = bf2f(ar[k]);
    const float* wr = W + (size_t)k * 9;
    #pragma unroll
    for (int j = 0; j < 9; ++j) acc[j] += a * wr[j];
  }
  #pragma unroll
  for (int j = 0; j < 9; ++j) {
    float sv = acc[j];
    for (int d = 32; d; d >>= 1) sv += __shfl_down(sv, d);
    if (l == 0) out[(size_t)wid * 9 + j] = BIAS ? (sv + bias[j]) : sv;
  }
}
__global__ __launch_bounds__(256) void skinny6(const unsigned short* __restrict__ A,
                                               const float* __restrict__ W,  // [6][1024]
                                               float* __restrict__ out) {
  int wid = blockIdx.x * 4 + (threadIdx.x >> 6);
  int l = threadIdx.x & 63;
  const unsigned short* ar = A + (size_t)wid * HID;
  float acc[6] = {};
  for (int i = 0; i < 4; ++i) {
    int k = i * 256 + l * 4;
    ushort4v av = *(const ushort4v*)(ar + k);
    float a0 = bf2f(av[0]), a1 = bf2f(av[1]), a2 = bf2f(av[2]), a3 = bf2f(av[3]);
    #pragma unroll
    for (int j = 0; j < 6; ++j) {
      float4 wv = *(const float4*)(W + (size_t)j * HID + k);
      acc[j] += a0 * wv.x + a1 * wv.y + a2 * wv.z + a3 * wv.w;
    }
  }
  #pragma unroll
  for (int j = 0; j < 6; ++j) {
    float sv = acc[j];
    for (int d = 32; d; d >>= 1) sv += __shfl_down(sv, d);
    if (l == 0) out[(size_t)wid * 6 + j] = sv;
  }
}
__global__ __launch_bounds__(256) void skinny3(const unsigned short* __restrict__ A,
                                               const float* __restrict__ W,  // [1024][3]
                                               const float* __restrict__ bias,
                                               float* __restrict__ out) {
  int wid = blockIdx.x * 4 + (threadIdx.x >> 6);
  int l = threadIdx.x & 63;
  const unsigned short* ar = A + (size_t)wid * HID;
  float a0 = 0.f, a1 = 0.f, a2 = 0.f;
  for (int i = 0; i < 16; ++i) {
    int k = i * 64 + l;
    float a = bf2f(ar[k]);
    const float* wr = W + (size_t)k * 3;
    a0 += a * wr[0]; a1 += a * wr[1]; a2 += a * wr[2];
  }
  float acc[3] = {a0, a1, a2};
  #pragma unroll
  for (int j = 0; j < 3; ++j) {
    float sv = acc[j];
    for (int d = 32; d; d >>= 1) sv += __shfl_down(sv, d);
    if (l == 0) out[(size_t)wid * 3 + j] = sv + bias[j];
  }
}

// ---------------- per-row 3x3 algebra
__global__ __launch_bounds__(256) void rowA(const float* __restrict__ x,
                                            const float* __restrict__ sLvec,
                                            float* __restrict__ sP,
                                            float* __restrict__ sGL) {
  int r = blockIdx.x * 256 + threadIdx.x;
  const float* Lv = sLvec + (size_t)r * 9;
  float L[3][3];
  #pragma unroll
  for (int i = 0; i < 3; ++i)
    #pragma unroll
    for (int j = 0; j < 3; ++j) L[i][j] = Lv[3 * i + j];
  float a = 0.1f, b = 0.f, c = 0.f, d = 0.1f, e = 0.f, f = 0.1f;
  #pragma unroll
  for (int k = 0; k < 3; ++k) {
    a += L[0][k] * L[0][k]; b += L[0][k] * L[1][k]; c += L[0][k] * L[2][k];
    d += L[1][k] * L[1][k]; e += L[1][k] * L[2][k]; f += L[2][k] * L[2][k];
  }
  const float* xr = x + (size_t)r * 10;
  float q0 = xr[6], q1 = xr[7], q2 = xr[8];
  float c00 = d * f - e * e;
  float c01 = c * e - b * f;
  float c02 = b * e - c * d;
  float det = a * c00 + b * c01 + c * c02;
  float inv = 1.f / det;
  float i00 = c00 * inv, i01 = c01 * inv, i02 = c02 * inv;
  float i11 = (a * f - c * c) * inv;
  float i12 = (b * c - a * e) * inv;
  float i22 = (a * d - b * b) * inv;
  float p0 = i00 * q0 + i01 * q1 + i02 * q2;
  float p1 = i01 * q0 + i11 * q1 + i12 * q2;
  float p2 = i02 * q0 + i12 * q1 + i22 * q2;
  sP[(size_t)r * 3 + 0] = p0; sP[(size_t)r * 3 + 1] = p1; sP[(size_t)r * 3 + 2] = p2;
  float lt0 = p0 * L[0][0] + p1 * L[1][0] + p2 * L[2][0];
  float lt1 = p0 * L[0][1] + p1 * L[1][1] + p2 * L[2][1];
  float lt2 = p0 * L[0][2] + p1 * L[1][2] + p2 * L[2][2];
  float pp[3] = {p0, p1, p2}, lt[3] = {lt0, lt1, lt2};
  #pragma unroll
  for (int i = 0; i < 3; ++i)
    #pragma unroll
    for (int j = 0; j < 3; ++j) sGL[(size_t)r * 9 + 3 * i + j] = pp[i] * lt[j];
}

__global__ __launch_bounds__(256) void rowB(const float* __restrict__ x,
                                            const float* __restrict__ sGzM,
                                            const float* __restrict__ sGzV,
                                            const float* __restrict__ sGq,
                                            float* __restrict__ out,
                                            float* __restrict__ sDp) {
  int r = blockIdx.x * 256 + threadIdx.x;
  const float* xr = x + (size_t)r * 10;
  float u = xr[9];
  #pragma unroll
  for (int i = 0; i < 3; ++i) {
    float cosq = xr[i], sinq = xr[3 + i], qd = xr[6 + i];
    float dhc = sGzM[(size_t)r * 6 + i] + sGzV[(size_t)r * 6 + i];
    float dhs = sGzM[(size_t)r * 6 + 3 + i] + sGzV[(size_t)r * 6 + 3 + i];
    float F = sGq[(size_t)r * 3 + i] * u;
    float dq = qd;  // dHdp = M_inv @ p = q_dot exactly
    float dp = sinq * dhc - cosq * dhs + F;
    out[(size_t)r * 10 + i]     = -sinq * dq;
    out[(size_t)r * 10 + 3 + i] =  cosq * dq;
    sDp[(size_t)r * 3 + i] = dp;
  }
}

__global__ __launch_bounds__(256) void rowC(const float* __restrict__ sLvec,
                                            const float* __restrict__ sTL,
                                            const float* __restrict__ sP,
                                            const float* __restrict__ sDp,
                                            float* __restrict__ out) {
  int r = blockIdx.x * 256 + threadIdx.x;
  float L[3][3], T[3][3];
  #pragma unroll
  for (int i = 0; i < 3; ++i)
    #pragma unroll
    for (int j = 0; j < 3; ++j) {
      L[i][j] = sLvec[(size_t)r * 9 + 3 * i + j];
      T[i][j] = sTL[(size_t)r * 9 + 3 * i + j];
    }
  float Mi[3][3], dM[3][3];
  #pragma unroll
  for (int i = 0; i < 3; ++i) {
    #pragma unroll
    for (int j = 0; j < 3; ++j) {
      float s = 0.f, sd = 0.f;
      #pragma unroll
      for (int k = 0; k < 3; ++k) {
        s  += L[i][k] * L[j][k];
        sd += T[i][k] * L[j][k] + L[i][k] * T[j][k];
      }
      Mi[i][j] = s + (i == j ? 0.1f : 0.f);
      dM[i][j] = sd;
    }
  }
  float p[3], dp[3];
  #pragma unroll
  for (int i = 0; i < 3; ++i) { p[i] = sP[(size_t)r * 3 + i]; dp[i] = sDp[(size_t)r * 3 + i]; }
  #pragma unroll
  for (int i = 0; i < 3; ++i) {
    float s = 0.f;
    #pragma unroll
    for (int j = 0; j < 3; ++j) s += Mi[i][j] * dp[j] + dM[i][j] * p[j];
    out[(size_t)r * 10 + 6 + i] = s;
  }
  out[(size_t)r * 10 + 9] = 0.f;
}

// ---------------- host
extern "C" void kernel_launch(void* const* d_in, const int* in_sizes, int n_in,
                              void* d_out, int out_size, void* d_ws, size_t ws_size,
                              hipStream_t stream) {
  const float* x   = (const float*)d_in[1];
  const float* MW1 = (const float*)d_in[2];
  const float* Mb1 = (const float*)d_in[3];
  const float* MW2 = (const float*)d_in[4];
  const float* Mb2 = (const float*)d_in[5];
  const float* MW3 = (const float*)d_in[6];
  const float* Mb3 = (const float*)d_in[7];
  const float* VW1 = (const float*)d_in[8];
  const float* Vb1 = (const float*)d_in[9];
  const float* VW2 = (const float*)d_in[10];
  const float* Vb2 = (const float*)d_in[11];
  const float* VW3 = (const float*)d_in[12];
  const float* GW1 = (const float*)d_in[14];
  const float* Gb1 = (const float*)d_in[15];
  const float* GW2 = (const float*)d_in[16];
  const float* Gb2 = (const float*)d_in[17];
  const float* GW3 = (const float*)d_in[18];
  const float* Gb3 = (const float*)d_in[19];
  float* out = (float*)d_out;
  char* ws = (char*)d_ws;

  const size_t PK  = (size_t)HID * HID * 2;
  const size_t BUF = (size_t)BS * HID * 2;
  const size_t NEED = 5 * PK + 3 * BUF + (size_t)BS * 48 * 4;
  if (ws_size < NEED) return;  // ws too small: fail visibly (output untouched)

  unsigned short* MW2p  = (unsigned short*)(ws + 0 * PK);
  unsigned short* MW2tp = (unsigned short*)(ws + 1 * PK);
  unsigned short* VW2p  = (unsigned short*)(ws + 2 * PK);
  unsigned short* VW2tp = (unsigned short*)(ws + 3 * PK);
  unsigned short* GW2p  = (unsigned short*)(ws + 4 * PK);
  unsigned short* P = (unsigned short*)(ws + 5 * PK);
  unsigned short* Q = (unsigned short*)(ws + 5 * PK + BUF);
  unsigned short* R = (unsigned short*)(ws + 5 * PK + 2 * BUF);
  char* s = ws + 5 * PK + 3 * BUF;
  float* sLvec = (float*)(s);
  float* sP    = (float*)(s + (size_t)BS *  9 * 4);
  float* sGL   = (float*)(s + (size_t)BS * 12 * 4);
  float* sGzM  = (float*)(s + (size_t)BS * 21 * 4);
  float* sGzV  = (float*)(s + (size_t)BS * 27 * 4);
  float* sGq   = (float*)(s + (size_t)BS * 33 * 4);
  float* sDp   = (float*)(s + (size_t)BS * 36 * 4);
  float* sTL   = (float*)(s + (size_t)BS * 39 * 4);

  dim3 B(256);
  dim3 BG(512);
  const int G_GEMM = 512;            // 128 mt x 4 nt
  const int G_EW   = BS * 128 / 256; // 16384
  const int G_SK   = BS / 4;         // 8192
  const int G_ROW  = BS / 256;       // 128

  // weight packing
  pack_w<<<256, B, 0, stream>>>(MW2, MW2p, MW2tp);
  pack_w<<<256, B, 0, stream>>>(VW2, VW2p, VW2tp);
  pack_w<<<256, B, 0, stream>>>(GW2, GW2p, nullptr);

  // M forward
  l1fwd<<<G_EW, B, 0, stream>>>(x, MW1, Mb1, P);                                  // h1M
  gemm_bf16<0><<<G_GEMM, BG, 0, stream>>>(P, MW2p, Q, Mb2, nullptr, nullptr, nullptr, nullptr); // h2M
  skinny9<true><<<G_SK, B, 0, stream>>>(Q, MW3, Mb3, sLvec);                      // Lvec
  rowA<<<G_ROW, B, 0, stream>>>(x, sLvec, sP, sGL);                               // p, gL
  mapQ<<<G_EW, B, 0, stream>>>(Q);                                                // Q := 1-h2^2

  // M backward -> gzM
  k9bwd<<<G_EW, B, 0, stream>>>(sGL, MW3, Q, P);                                  // g2
  gemm_bf16<2><<<G_GEMM, BG, 0, stream>>>(P, MW2tp, R, nullptr, nullptr, x, MW1, Mb1); // g1
  skinny6<<<G_SK, B, 0, stream>>>(R, MW1, sGzM);

  // G forward -> g_q
  l1fwd<<<G_EW, B, 0, stream>>>(x, GW1, Gb1, P);
  gemm_bf16<0><<<G_GEMM, BG, 0, stream>>>(P, GW2p, R, Gb2, nullptr, nullptr, nullptr, nullptr);
  skinny3<<<G_SK, B, 0, stream>>>(R, GW3, Gb3, sGq);

  // V backward -> gzV
  l1fwd<<<G_EW, B, 0, stream>>>(x, VW1, Vb1, P);                                  // vh1
  gemm_bf16<0><<<G_GEMM, BG, 0, stream>>>(P, VW2p, R, Vb2, nullptr, nullptr, nullptr, nullptr); // vh2
  mapV<<<G_EW, B, 0, stream>>>(R, VW3);                                           // gv2
  gemm_bf16<2><<<G_GEMM, BG, 0, stream>>>(R, VW2tp, P, nullptr, nullptr, x, VW1, Vb1); // gv1
  skinny6<<<G_SK, B, 0, stream>>>(P, VW1, sGzV);

  // assemble tangent, dp; write out[:, 0:6]
  rowB<<<G_ROW, B, 0, stream>>>(x, sGzM, sGzV, sGq, out, sDp);

  // JVP through M-net
  l1t<<<G_EW, B, 0, stream>>>(x, out, MW1, Mb1, P);                               // th1
  gemm_bf16<1><<<G_GEMM, BG, 0, stream>>>(P, MW2p, R, nullptr, Q, nullptr, nullptr, nullptr); // th2
  skinny9<false><<<G_SK, B, 0, stream>>>(R, MW3, nullptr, sTL);                   // tLvec

  // final: ddq; write out[:, 6:10]
  rowC<<<G_ROW, B, 0, stream>>>(sLvec, sTL, sP, sDp, out);
}

// Round 11
// 1077.620 us; speedup vs baseline: 1.3083x; 1.3083x over previous
//
#include <hip/hip_runtime.h>

// HNN structure embed (N=3, HID=1024, bs=32768).
// GEMMs: bf16 MFMA 16x16x32, 128x128x64 tiles, 2-slot LDS ring (64 KB),
// minimal 2-phase loop (catalog-verified): STAGE(next) -> COMPUTE(cur) ->
// vmcnt(0) -> ONE barrier per tile. K-loop unrolled by 2 so both LDS slot
// bases are compile-time constants (loop-invariant ds_read addressing).
// R9 register discipline: one A-fragment at a time, voff[4] shared staging
// offsets, full-unroll epilogue + sched_barrier(0) per m-chunk.
// mapQ eliminated: d2 = 1-h2^2 computed inline in k9bwd and EPI1.
// Per-row 3x3 algebra in f32. dHdp == q_dot (exact). V layer-3 fwd skipped.

#define HID 1024
#define BS  32768

typedef __attribute__((ext_vector_type(8))) short short8;
typedef __attribute__((ext_vector_type(4))) float f32x4;
typedef __attribute__((ext_vector_type(8))) unsigned short ushort8v;
typedef __attribute__((ext_vector_type(4))) unsigned short ushort4v;

typedef __attribute__((address_space(1))) const char gconst_char;
typedef __attribute__((address_space(3))) char lds_char;

__device__ __forceinline__ unsigned short f2bf(float f) {
  unsigned int u = __builtin_bit_cast(unsigned int, f);
  u += 0x7fffu + ((u >> 16) & 1u);   // RNE
  return (unsigned short)(u >> 16);
}
__device__ __forceinline__ float bf2f(unsigned short s) {
  unsigned int u = ((unsigned int)s) << 16;
  return __builtin_bit_cast(float, u);
}
__device__ __forceinline__ float tanh_fast(float x) {
  float e = __builtin_amdgcn_exp2f(x * 2.885390081777927f); // e^(2x)
  return 1.f - 2.f * __builtin_amdgcn_rcpf(e + 1.f);
}

// ---------------- weight packing: pT[n][k]=bf16(W[k][n]); pC[n][k]=bf16(W[n][k])
__global__ __launch_bounds__(256) void pack_w(const float* __restrict__ W,
                                              unsigned short* __restrict__ pT,
                                              unsigned short* __restrict__ pC) {
  __shared__ float tile[64][65];
  int b = blockIdx.x;
  int k0 = (b >> 4) << 6;
  int n0 = (b & 15) << 6;
  int t = threadIdx.x;
  for (int i = 0; i < 16; ++i) {
    int idx = i * 256 + t;
    int r = idx >> 6, c = idx & 63;
    tile[r][c] = W[(size_t)(k0 + r) * HID + n0 + c];
  }
  if (pC) {
    for (int i = 0; i < 16; ++i) {
      int idx = i * 256 + t;
      int r = idx >> 6, c = idx & 63;
      pC[(size_t)(n0 + r) * HID + k0 + c] = f2bf(W[(size_t)(n0 + r) * HID + k0 + c]);
    }
  }
  __syncthreads();
  for (int i = 0; i < 16; ++i) {
    int idx = i * 256 + t;
    int n = idx >> 6, k = idx & 63;
    pT[(size_t)(n0 + n) * HID + k0 + k] = f2bf(tile[k][n]);
  }
}

// ---------------- big GEMM: C[m][n] = epi( sum_k A[m][k]*Bp[n][k] )
// EPI 0: tanh(acc + bias[col])
// EPI 1: acc * (1 - bf2f(aux[row][col])^2)              (aux = raw h2)
// EPI 2: acc * (1 - tanh(x6[row]@W1[:,col] + b1[col])^2)  (recompute d1)
template<int EPI>
__global__ __launch_bounds__(256) void gemm_bf16(
    const unsigned short* __restrict__ A,
    const unsigned short* __restrict__ Bp,
    unsigned short* __restrict__ C,
    const float* __restrict__ bias,
    const unsigned short* __restrict__ aux,
    const float* __restrict__ xall,
    const float* __restrict__ W1,
    const float* __restrict__ b1)
{
  __shared__ __align__(1024) char lds[65536];   // 2 x (A 16K + B 16K)
  const int t = threadIdx.x;
  const int w = t >> 6, l = t & 63;
  // bijective XCD swizzle: 2048 blocks, 8 XCDs -> each XCD owns 32 M-panels
  int bid = (int)blockIdx.x;
  int wg  = (bid & 7) * 256 + (bid >> 3);
  const int nt = wg & 7, mt = wg >> 3;
  const int r0 = mt << 7, n0 = nt << 7;
  const int wr = w >> 1, wc = w & 1;

  f32x4 acc[4][4] = {};
  const int lbase = (w << 2);

  // single lane-offset array shared by A and B staging (identical formula)
  int voff[4];
  #pragma unroll
  for (int i = 0; i < 4; ++i) {
    int o   = ((lbase + i) << 10) + (l << 4);
    int row = o >> 7;
    voff[i] = (row << 11) + ((o & 127) ^ ((row & 7) << 4));
  }
  const char* Abase = (const char*)A  + ((size_t)r0 << 11);
  const char* Bbase = (const char*)Bp + ((size_t)n0 << 11);

  // stage K-tile kt into slot with base `Ad` (compile-time pointer)
  auto STAGE = [&](char* Ad, int kt) {
    char* Bd = Ad + 16384;
    const char* Ak = Abase + kt * 128;
    const char* Bk = Bbase + kt * 128;
    #pragma unroll
    for (int i = 0; i < 4; ++i) {
      __builtin_amdgcn_global_load_lds((gconst_char*)(Ak + voff[i]), (lds_char*)(Ad + ((lbase + i) << 10)), 16, 0, 0);
      __builtin_amdgcn_global_load_lds((gconst_char*)(Bk + voff[i]), (lds_char*)(Bd + ((lbase + i) << 10)), 16, 0, 0);
    }
  };

  auto COMPUTE = [&](const char* As) {
    const char* Bs = As + 16384;
    #pragma unroll
    for (int kk = 0; kk < 2; ++kk) {
      short8 bfr[4];
      #pragma unroll
      for (int n = 0; n < 4; ++n) {
        int col = (wc << 6) + (n << 4) + (l & 15);
        int off = (col << 7) + ((l >> 4) << 4) + (kk << 6);
        off ^= ((col & 7) << 4);
        bfr[n] = *(const short8*)(Bs + off);
      }
      #pragma unroll
      for (int m = 0; m < 4; ++m) {
        int row = (wr << 6) + (m << 4) + (l & 15);
        int off = (row << 7) + ((l >> 4) << 4) + (kk << 6);
        off ^= ((row & 7) << 4);
        short8 af = *(const short8*)(As + off);
        #pragma unroll
        for (int n = 0; n < 4; ++n) {
          acc[m][n] = __builtin_amdgcn_mfma_f32_16x16x32_bf16(af, bfr[n], acc[m][n], 0, 0, 0);
        }
      }
    }
  };

  char* L0 = lds;
  char* L1 = lds + 32768;

  // prologue: tile 0 into L0, drain, sync
  STAGE(L0, 0);
  asm volatile("s_waitcnt vmcnt(0)" ::: "memory");
  __builtin_amdgcn_s_barrier();

  // minimal 2-phase: STAGE(next) -> COMPUTE(cur) -> vmcnt(0) -> barrier.
  // Unrolled x2 so L0/L1 are compile-time bases (loop-invariant addressing).
  #pragma unroll 1
  for (int kt2 = 0; kt2 < 7; ++kt2) {
    STAGE(L1, 2 * kt2 + 1);
    COMPUTE(L0);
    asm volatile("s_waitcnt vmcnt(0)" ::: "memory");
    __builtin_amdgcn_s_barrier();
    STAGE(L0, 2 * kt2 + 2);
    COMPUTE(L1);
    asm volatile("s_waitcnt vmcnt(0)" ::: "memory");
    __builtin_amdgcn_s_barrier();
  }
  // kt = 14: stage tile 15, compute tile 14 (in L0)
  STAGE(L1, 15);
  COMPUTE(L0);
  asm volatile("s_waitcnt vmcnt(0)" ::: "memory");
  __builtin_amdgcn_s_barrier();
  // kt = 15
  COMPUTE(L1);
  __syncthreads();   // ds_reads retired before epilogue reuses LDS

  // epilogue: FULL unroll (compile-time acc indices -> AGPR, no scratch);
  // sched_barrier(0) after each m-chunk caps the accvgpr-read live range.
  char* Cs = lds;
  #pragma unroll
  for (int n = 0; n < 4; ++n) {
    const int colL = (wc << 6) + (n << 4) + (l & 15);
    const int gcol = n0 + colL;
    float bval = 0.f;
    float w1c[6];
    if (EPI == 0) bval = bias[gcol];
    if (EPI == 2) {
      bval = b1[gcol];
      #pragma unroll
      for (int k2 = 0; k2 < 6; ++k2) w1c[k2] = W1[k2 * HID + gcol];
    }
    #pragma unroll
    for (int m = 0; m < 4; ++m) {
      #pragma unroll
      for (int r = 0; r < 4; ++r) {
        const int rowL = (wr << 6) + (m << 4) + ((l >> 4) << 2) + r;
        float v = acc[m][n][r];
        if (EPI == 0) {
          v = tanh_fast(v + bval);
        } else if (EPI == 1) {
          float h = bf2f(aux[((size_t)(r0 + rowL) << 10) + gcol]);
          v *= (1.f - h * h);
        } else {
          const float* xr = xall + (size_t)(r0 + rowL) * 10;
          float z = bval;
          #pragma unroll
          for (int k2 = 0; k2 < 6; ++k2) z += xr[k2] * w1c[k2];
          float th = tanh_fast(z);
          v *= (1.f - th * th);
        }
        int so = (rowL << 8) + (colL << 1);
        so ^= ((rowL & 7) << 5);
        *(unsigned short*)(Cs + so) = f2bf(v);
      }
      __builtin_amdgcn_sched_barrier(0);   // cap live acc reads per chunk
    }
  }
  __syncthreads();
  #pragma unroll
  for (int j = 0; j < 8; ++j) {
    int o    = (j << 12) + (t << 4);
    int rowL = o >> 8;
    int ir   = o & 255;
    uint4 v = *(const uint4*)(Cs + ((rowL << 8) + (ir ^ ((rowL & 7) << 5))));
    *(uint4*)(C + ((size_t)(r0 + rowL) << 10) + n0 + (ir >> 1)) = v;
  }
}

// ---------------- layer-1 forward: out = tanh(x6 @ W1 + b1), bf16
__global__ __launch_bounds__(256) void l1fwd(const float* __restrict__ x,
                                             const float* __restrict__ W1,
                                             const float* __restrict__ b1,
                                             unsigned short* __restrict__ out) {
  int idx = blockIdx.x * 256 + threadIdx.x;
  int r = idx >> 7;
  int n8 = (idx & 127) << 3;
  const float* xr = x + (size_t)r * 10;
  float xs[6];
  #pragma unroll
  for (int k = 0; k < 6; ++k) xs[k] = xr[k];
  float4 bb0 = *(const float4*)(b1 + n8), bb1 = *(const float4*)(b1 + n8 + 4);
  float z[8] = {bb0.x, bb0.y, bb0.z, bb0.w, bb1.x, bb1.y, bb1.z, bb1.w};
  #pragma unroll
  for (int k = 0; k < 6; ++k) {
    const float* wrow = W1 + (size_t)k * HID + n8;
    float4 wa = *(const float4*)wrow, wb = *(const float4*)(wrow + 4);
    z[0] += xs[k] * wa.x; z[1] += xs[k] * wa.y; z[2] += xs[k] * wa.z; z[3] += xs[k] * wa.w;
    z[4] += xs[k] * wb.x; z[5] += xs[k] * wb.y; z[6] += xs[k] * wb.z; z[7] += xs[k] * wb.w;
  }
  ushort8v o;
  #pragma unroll
  for (int j = 0; j < 8; ++j) o[j] = f2bf(tanh_fast(z[j]));
  *(ushort8v*)(out + (size_t)r * HID + n8) = o;
}

// ---------------- JVP layer-1: th1 = (tang @ W1) * (1 - tanh(x@W1+b1)^2)
__global__ __launch_bounds__(256) void l1t(const float* __restrict__ x,
                                           const float* __restrict__ outbuf, // tangent in cols 0..5
                                           const float* __restrict__ W1,
                                           const float* __restrict__ b1,
                                           unsigned short* __restrict__ P) {
  int idx = blockIdx.x * 256 + threadIdx.x;
  int r = idx >> 7;
  int n8 = (idx & 127) << 3;
  const float* xr = x + (size_t)r * 10;
  const float* tr = outbuf + (size_t)r * 10;
  float xs[6], ts[6];
  #pragma unroll
  for (int k = 0; k < 6; ++k) { xs[k] = xr[k]; ts[k] = tr[k]; }
  float4 bb0 = *(const float4*)(b1 + n8), bb1 = *(const float4*)(b1 + n8 + 4);
  float z[8] = {bb0.x, bb0.y, bb0.z, bb0.w, bb1.x, bb1.y, bb1.z, bb1.w};
  float tz[8] = {};
  #pragma unroll
  for (int k = 0; k < 6; ++k) {
    const float* wrow = W1 + (size_t)k * HID + n8;
    float4 wa = *(const float4*)wrow, wb = *(const float4*)(wrow + 4);
    z[0] += xs[k] * wa.x;  z[1] += xs[k] * wa.y;  z[2] += xs[k] * wa.z;  z[3] += xs[k] * wa.w;
    z[4] += xs[k] * wb.x;  z[5] += xs[k] * wb.y;  z[6] += xs[k] * wb.z;  z[7] += xs[k] * wb.w;
    tz[0] += ts[k] * wa.x; tz[1] += ts[k] * wa.y; tz[2] += ts[k] * wa.z; tz[3] += ts[k] * wa.w;
    tz[4] += ts[k] * wb.x; tz[5] += ts[k] * wb.y; tz[6] += ts[k] * wb.z; tz[7] += ts[k] * wb.w;
  }
  ushort8v o;
  #pragma unroll
  for (int j = 0; j < 8; ++j) {
    float th = tanh_fast(z[j]);
    o[j] = f2bf(tz[j] * (1.f - th * th));
  }
  *(ushort8v*)(P + (size_t)r * HID + n8) = o;
}

// ---------------- g2 = (gL @ MW3^T) * (1-h2^2), bf16  (K = 9, h2 raw)
__global__ __launch_bounds__(256) void k9bwd(const float* __restrict__ sGL,
                                             const float* __restrict__ MW3, // [1024][9]
                                             const unsigned short* __restrict__ h2,
                                             unsigned short* __restrict__ outp) {
  int idx = blockIdx.x * 256 + threadIdx.x;
  int r = idx >> 7;
  int n8 = (idx & 127) << 3;
  const float* g = sGL + (size_t)r * 9;
  float gl[9];
  #pragma unroll
  for (int j = 0; j < 9; ++j) gl[j] = g[j];
  ushort8v dv = *(const ushort8v*)(h2 + (size_t)r * HID + n8);
  ushort8v o;
  #pragma unroll
  for (int j = 0; j < 8; ++j) {
    const float* wr = MW3 + (size_t)(n8 + j) * 9;
    float s = 0.f;
    #pragma unroll
    for (int jj = 0; jj < 9; ++jj) s += gl[jj] * wr[jj];
    float h = bf2f(dv[j]);
    o[j] = f2bf(s * (1.f - h * h));
  }
  *(ushort8v*)(outp + (size_t)r * HID + n8) = o;
}

// ---------------- mapV: Rb := VW3[col] * (1 - Rb^2)
__global__ __launch_bounds__(256) void mapV(unsigned short* __restrict__ Rb,
                                            const float* __restrict__ VW3) {
  int idx = blockIdx.x * 256 + threadIdx.x;
  int r = idx >> 7;
  int n8 = (idx & 127) << 3;
  ushort8v v = *(ushort8v*)(Rb + (size_t)r * HID + n8);
  float4 w0 = *(const float4*)(VW3 + n8), w1 = *(const float4*)(VW3 + n8 + 4);
  float wv[8] = {w0.x, w0.y, w0.z, w0.w, w1.x, w1.y, w1.z, w1.w};
  #pragma unroll
  for (int j = 0; j < 8; ++j) { float f = bf2f(v[j]); v[j] = f2bf(wv[j] * (1.f - f * f)); }
  *(ushort8v*)(Rb + (size_t)r * HID + n8) = v;
}

// ---------------- skinny reductions (wave per row)
template<bool BIAS>
__global__ __launch_bounds__(256) void skinny9(const unsigned short* __restrict__ A,
                                               const float* __restrict__ W,  // [1024][9]
                                               const float* __restrict__ bias,
                                               float* __restrict__ out) {
  int wid = blockIdx.x * 4 + (threadIdx.x >> 6);
  int l = threadIdx.x & 63;
  const unsigned short* ar = A + (size_t)wid * HID;
  float acc[9] = {};
  for (int i = 0; i < 16; ++i) {
    int k = i * 64 + l;
    float a = bf2f(ar[k]);
    const float* wr = W + (size_t)k * 9;
    #pragma unroll
    for (int j = 0; j < 9; ++j) acc[j] += a * wr[j];
  }
  #pragma unroll
  for (int j = 0; j < 9; ++j) {
    float sv = acc[j];
    for (int d = 32; d; d >>= 1) sv += __shfl_down(sv, d);
    if (l == 0) out[(size_t)wid * 9 + j] = BIAS ? (sv + bias[j]) : sv;
  }
}
__global__ __launch_bounds__(256) void skinny6(const unsigned short* __restrict__ A,
                                               const float* __restrict__ W,  // [6][1024]
                                               float* __restrict__ out) {
  int wid = blockIdx.x * 4 + (threadIdx.x >> 6);
  int l = threadIdx.x & 63;
  const unsigned short* ar = A + (size_t)wid * HID;
  float acc[6] = {};
  for (int i = 0; i < 4; ++i) {
    int k = i * 256 + l * 4;
    ushort4v av = *(const ushort4v*)(ar + k);
    float a0 = bf2f(av[0]), a1 = bf2f(av[1]), a2 = bf2f(av[2]), a3 = bf2f(av[3]);
    #pragma unroll
    for (int j = 0; j < 6; ++j) {
      float4 wv = *(const float4*)(W + (size_t)j * HID + k);
      acc[j] += a0 * wv.x + a1 * wv.y + a2 * wv.z + a3 * wv.w;
    }
  }
  #pragma unroll
  for (int j = 0; j < 6; ++j) {
    float sv = acc[j];
    for (int d = 32; d; d >>= 1) sv += __shfl_down(sv, d);
    if (l == 0) out[(size_t)wid * 6 + j] = sv;
  }
}
__global__ __launch_bounds__(256) void skinny3(const unsigned short* __restrict__ A,
                                               const float* __restrict__ W,  // [1024][3]
                                               const float* __restrict__ bias,
                                               float* __restrict__ out) {
  int wid = blockIdx.x * 4 + (threadIdx.x >> 6);
  int l = threadIdx.x & 63;
  const unsigned short* ar = A + (size_t)wid * HID;
  float a0 = 0.f, a1 = 0.f, a2 = 0.f;
  for (int i = 0; i < 16; ++i) {
    int k = i * 64 + l;
    float a = bf2f(ar[k]);
    const float* wr = W + (size_t)k * 3;
    a0 += a * wr[0]; a1 += a * wr[1]; a2 += a * wr[2];
  }
  float acc[3] = {a0, a1, a2};
  #pragma unroll
  for (int j = 0; j < 3; ++j) {
    float sv = acc[j];
    for (int d = 32; d; d >>= 1) sv += __shfl_down(sv, d);
    if (l == 0) out[(size_t)wid * 3 + j] = sv + bias[j];
  }
}

// ---------------- per-row 3x3 algebra
__global__ __launch_bounds__(256) void rowA(const float* __restrict__ x,
                                            const float* __restrict__ sLvec,
                                            float* __restrict__ sP,
                                            float* __restrict__ sGL) {
  int r = blockIdx.x * 256 + threadIdx.x;
  const float* Lv = sLvec + (size_t)r * 9;
  float L[3][3];
  #pragma unroll
  for (int i = 0; i < 3; ++i)
    #pragma unroll
    for (int j = 0; j < 3; ++j) L[i][j] = Lv[3 * i + j];
  float a = 0.1f, b = 0.f, c = 0.f, d = 0.1f, e = 0.f, f = 0.1f;
  #pragma unroll
  for (int k = 0; k < 3; ++k) {
    a += L[0][k] * L[0][k]; b += L[0][k] * L[1][k]; c += L[0][k] * L[2][k];
    d += L[1][k] * L[1][k]; e += L[1][k] * L[2][k]; f += L[2][k] * L[2][k];
  }
  const float* xr = x + (size_t)r * 10;
  float q0 = xr[6], q1 = xr[7], q2 = xr[8];
  float c00 = d * f - e * e;
  float c01 = c * e - b * f;
  float c02 = b * e - c * d;
  float det = a * c00 + b * c01 + c * c02;
  float inv = 1.f / det;
  float i00 = c00 * inv, i01 = c01 * inv, i02 = c02 * inv;
  float i11 = (a * f - c * c) * inv;
  float i12 = (b * c - a * e) * inv;
  float i22 = (a * d - b * b) * inv;
  float p0 = i00 * q0 + i01 * q1 + i02 * q2;
  float p1 = i01 * q0 + i11 * q1 + i12 * q2;
  float p2 = i02 * q0 + i12 * q1 + i22 * q2;
  sP[(size_t)r * 3 + 0] = p0; sP[(size_t)r * 3 + 1] = p1; sP[(size_t)r * 3 + 2] = p2;
  float lt0 = p0 * L[0][0] + p1 * L[1][0] + p2 * L[2][0];
  float lt1 = p0 * L[0][1] + p1 * L[1][1] + p2 * L[2][1];
  float lt2 = p0 * L[0][2] + p1 * L[1][2] + p2 * L[2][2];
  float pp[3] = {p0, p1, p2}, lt[3] = {lt0, lt1, lt2};
  #pragma unroll
  for (int i = 0; i < 3; ++i)
    #pragma unroll
    for (int j = 0; j < 3; ++j) sGL[(size_t)r * 9 + 3 * i + j] = pp[i] * lt[j];
}

__global__ __launch_bounds__(256) void rowB(const float* __restrict__ x,
                                            const float* __restrict__ sGzM,
                                            const float* __restrict__ sGzV,
                                            const float* __restrict__ sGq,
                                            float* __restrict__ out,
                                            float* __restrict__ sDp) {
  int r = blockIdx.x * 256 + threadIdx.x;
  const float* xr = x + (size_t)r * 10;
  float u = xr[9];
  #pragma unroll
  for (int i = 0; i < 3; ++i) {
    float cosq = xr[i], sinq = xr[3 + i], qd = xr[6 + i];
    float dhc = sGzM[(size_t)r * 6 + i] + sGzV[(size_t)r * 6 + i];
    float dhs = sGzM[(size_t)r * 6 + 3 + i] + sGzV[(size_t)r * 6 + 3 + i];
    float F = sGq[(size_t)r * 3 + i] * u;
    float dq = qd;  // dHdp = M_inv @ p = q_dot exactly
    float dp = sinq * dhc - cosq * dhs + F;
    out[(size_t)r * 10 + i]     = -sinq * dq;
    out[(size_t)r * 10 + 3 + i] =  cosq * dq;
    sDp[(size_t)r * 3 + i] = dp;
  }
}

__global__ __launch_bounds__(256) void rowC(const float* __restrict__ sLvec,
                                            const float* __restrict__ sTL,
                                            const float* __restrict__ sP,
                                            const float* __restrict__ sDp,
                                            float* __restrict__ out) {
  int r = blockIdx.x * 256 + threadIdx.x;
  float L[3][3], T[3][3];
  #pragma unroll
  for (int i = 0; i < 3; ++i)
    #pragma unroll
    for (int j = 0; j < 3; ++j) {
      L[i][j] = sLvec[(size_t)r * 9 + 3 * i + j];
      T[i][j] = sTL[(size_t)r * 9 + 3 * i + j];
    }
  float Mi[3][3], dM[3][3];
  #pragma unroll
  for (int i = 0; i < 3; ++i) {
    #pragma unroll
    for (int j = 0; j < 3; ++j) {
      float s = 0.f, sd = 0.f;
      #pragma unroll
      for (int k = 0; k < 3; ++k) {
        s  += L[i][k] * L[j][k];
        sd += T[i][k] * L[j][k] + L[i][k] * T[j][k];
      }
      Mi[i][j] = s + (i == j ? 0.1f : 0.f);
      dM[i][j] = sd;
    }
  }
  float p[3], dp[3];
  #pragma unroll
  for (int i = 0; i < 3; ++i) { p[i] = sP[(size_t)r * 3 + i]; dp[i] = sDp[(size_t)r * 3 + i]; }
  #pragma unroll
  for (int i = 0; i < 3; ++i) {
    float s = 0.f;
    #pragma unroll
    for (int j = 0; j < 3; ++j) s += Mi[i][j] * dp[j] + dM[i][j] * p[j];
    out[(size_t)r * 10 + 6 + i] = s;
  }
  out[(size_t)r * 10 + 9] = 0.f;
}

// ---------------- host
extern "C" void kernel_launch(void* const* d_in, const int* in_sizes, int n_in,
                              void* d_out, int out_size, void* d_ws, size_t ws_size,
                              hipStream_t stream) {
  const float* x   = (const float*)d_in[1];
  const float* MW1 = (const float*)d_in[2];
  const float* Mb1 = (const float*)d_in[3];
  const float* MW2 = (const float*)d_in[4];
  const float* Mb2 = (const float*)d_in[5];
  const float* MW3 = (const float*)d_in[6];
  const float* Mb3 = (const float*)d_in[7];
  const float* VW1 = (const float*)d_in[8];
  const float* Vb1 = (const float*)d_in[9];
  const float* VW2 = (const float*)d_in[10];
  const float* Vb2 = (const float*)d_in[11];
  const float* VW3 = (const float*)d_in[12];
  const float* GW1 = (const float*)d_in[14];
  const float* Gb1 = (const float*)d_in[15];
  const float* GW2 = (const float*)d_in[16];
  const float* Gb2 = (const float*)d_in[17];
  const float* GW3 = (const float*)d_in[18];
  const float* Gb3 = (const float*)d_in[19];
  float* out = (float*)d_out;
  char* ws = (char*)d_ws;

  const size_t PK  = (size_t)HID * HID * 2;
  const size_t BUF = (size_t)BS * HID * 2;
  const size_t NEED = 5 * PK + 3 * BUF + (size_t)BS * 48 * 4;
  if (ws_size < NEED) return;  // ws too small: fail visibly (output untouched)

  unsigned short* MW2p  = (unsigned short*)(ws + 0 * PK);
  unsigned short* MW2tp = (unsigned short*)(ws + 1 * PK);
  unsigned short* VW2p  = (unsigned short*)(ws + 2 * PK);
  unsigned short* VW2tp = (unsigned short*)(ws + 3 * PK);
  unsigned short* GW2p  = (unsigned short*)(ws + 4 * PK);
  unsigned short* P = (unsigned short*)(ws + 5 * PK);
  unsigned short* Q = (unsigned short*)(ws + 5 * PK + BUF);
  unsigned short* R = (unsigned short*)(ws + 5 * PK + 2 * BUF);
  char* s = ws + 5 * PK + 3 * BUF;
  float* sLvec = (float*)(s);
  float* sP    = (float*)(s + (size_t)BS *  9 * 4);
  float* sGL   = (float*)(s + (size_t)BS * 12 * 4);
  float* sGzM  = (float*)(s + (size_t)BS * 21 * 4);
  float* sGzV  = (float*)(s + (size_t)BS * 27 * 4);
  float* sGq   = (float*)(s + (size_t)BS * 33 * 4);
  float* sDp   = (float*)(s + (size_t)BS * 36 * 4);
  float* sTL   = (float*)(s + (size_t)BS * 39 * 4);

  dim3 B(256);
  const int G_GEMM = 2048;          // 256 mt x 8 nt
  const int G_EW   = BS * 128 / 256; // 16384
  const int G_SK   = BS / 4;         // 8192
  const int G_ROW  = BS / 256;       // 128

  // weight packing
  pack_w<<<256, B, 0, stream>>>(MW2, MW2p, MW2tp);
  pack_w<<<256, B, 0, stream>>>(VW2, VW2p, VW2tp);
  pack_w<<<256, B, 0, stream>>>(GW2, GW2p, nullptr);

  // M forward
  l1fwd<<<G_EW, B, 0, stream>>>(x, MW1, Mb1, P);                                  // h1M
  gemm_bf16<0><<<G_GEMM, B, 0, stream>>>(P, MW2p, Q, Mb2, nullptr, nullptr, nullptr, nullptr); // h2M (raw)
  skinny9<true><<<G_SK, B, 0, stream>>>(Q, MW3, Mb3, sLvec);                      // Lvec
  rowA<<<G_ROW, B, 0, stream>>>(x, sLvec, sP, sGL);                               // p, gL

  // M backward -> gzM  (d2 computed inline from raw h2)
  k9bwd<<<G_EW, B, 0, stream>>>(sGL, MW3, Q, P);                                  // g2
  gemm_bf16<2><<<G_GEMM, B, 0, stream>>>(P, MW2tp, R, nullptr, nullptr, x, MW1, Mb1); // g1
  skinny6<<<G_SK, B, 0, stream>>>(R, MW1, sGzM);

  // G forward -> g_q
  l1fwd<<<G_EW, B, 0, stream>>>(x, GW1, Gb1, P);
  gemm_bf16<0><<<G_GEMM, B, 0, stream>>>(P, GW2p, R, Gb2, nullptr, nullptr, nullptr, nullptr);
  skinny3<<<G_SK, B, 0, stream>>>(R, GW3, Gb3, sGq);

  // V backward -> gzV
  l1fwd<<<G_EW, B, 0, stream>>>(x, VW1, Vb1, P);                                  // vh1
  gemm_bf16<0><<<G_GEMM, B, 0, stream>>>(P, VW2p, R, Vb2, nullptr, nullptr, nullptr, nullptr); // vh2
  mapV<<<G_EW, B, 0, stream>>>(R, VW3);                                           // gv2
  gemm_bf16<2><<<G_GEMM, B, 0, stream>>>(R, VW2tp, P, nullptr, nullptr, x, VW1, Vb1); // gv1
  skinny6<<<G_SK, B, 0, stream>>>(P, VW1, sGzV);

  // assemble tangent, dp; write out[:, 0:6]
  rowB<<<G_ROW, B, 0, stream>>>(x, sGzM, sGzV, sGq, out, sDp);

  // JVP through M-net (aux = raw h2; EPI1 computes 1-h2^2 inline)
  l1t<<<G_EW, B, 0, stream>>>(x, out, MW1, Mb1, P);                               // th1
  gemm_bf16<1><<<G_GEMM, B, 0, stream>>>(P, MW2p, R, nullptr, Q, nullptr, nullptr, nullptr); // th2
  skinny9<false><<<G_SK, B, 0, stream>>>(R, MW3, nullptr, sTL);                   // tLvec

  // final: ddq; write out[:, 6:10]
  rowC<<<G_ROW, B, 0, stream>>>(sLvec, sTL, sP, sDp, out);
}

// Round 12
// 1028.330 us; speedup vs baseline: 1.3710x; 1.0479x over previous
//
#include <hip/hip_runtime.h>

// HNN structure embed (N=3, HID=1024, bs=32768).
// GEMMs: bf16 MFMA 16x16x32, 128x128x64 tiles, 2-slot LDS ring (64 KB),
// minimal 2-phase loop. R12: __launch_bounds__(256,2) on the LEAN kernel
// (R11 structure: voff sharing, af-at-a-time, fenced epilogue) to force
// arch VGPR <= 128 -> total (128+64 AGPR) = 192 <= empirical 2-block
// boundary (152->21% occ, 192->21%, 224+->11%). kk-level + store-level
// sched_barrier(0) fences cap live ranges so the allocator can meet 128
// without spilling (gate: FETCH/WRITE must stay ~60/65 MB).
// Per-row 3x3 algebra in f32. dHdp == q_dot (exact). V layer-3 fwd skipped.

#define HID 1024
#define BS  32768

typedef __attribute__((ext_vector_type(8))) short short8;
typedef __attribute__((ext_vector_type(4))) float f32x4;
typedef __attribute__((ext_vector_type(8))) unsigned short ushort8v;
typedef __attribute__((ext_vector_type(4))) unsigned short ushort4v;

typedef __attribute__((address_space(1))) const char gconst_char;
typedef __attribute__((address_space(3))) char lds_char;

__device__ __forceinline__ unsigned short f2bf(float f) {
  unsigned int u = __builtin_bit_cast(unsigned int, f);
  u += 0x7fffu + ((u >> 16) & 1u);   // RNE
  return (unsigned short)(u >> 16);
}
__device__ __forceinline__ float bf2f(unsigned short s) {
  unsigned int u = ((unsigned int)s) << 16;
  return __builtin_bit_cast(float, u);
}
__device__ __forceinline__ float tanh_fast(float x) {
  float e = __builtin_amdgcn_exp2f(x * 2.885390081777927f); // e^(2x)
  return 1.f - 2.f * __builtin_amdgcn_rcpf(e + 1.f);
}

// ---------------- weight packing: pT[n][k]=bf16(W[k][n]); pC[n][k]=bf16(W[n][k])
__global__ __launch_bounds__(256) void pack_w(const float* __restrict__ W,
                                              unsigned short* __restrict__ pT,
                                              unsigned short* __restrict__ pC) {
  __shared__ float tile[64][65];
  int b = blockIdx.x;
  int k0 = (b >> 4) << 6;
  int n0 = (b & 15) << 6;
  int t = threadIdx.x;
  for (int i = 0; i < 16; ++i) {
    int idx = i * 256 + t;
    int r = idx >> 6, c = idx & 63;
    tile[r][c] = W[(size_t)(k0 + r) * HID + n0 + c];
  }
  if (pC) {
    for (int i = 0; i < 16; ++i) {
      int idx = i * 256 + t;
      int r = idx >> 6, c = idx & 63;
      pC[(size_t)(n0 + r) * HID + k0 + c] = f2bf(W[(size_t)(n0 + r) * HID + k0 + c]);
    }
  }
  __syncthreads();
  for (int i = 0; i < 16; ++i) {
    int idx = i * 256 + t;
    int n = idx >> 6, k = idx & 63;
    pT[(size_t)(n0 + n) * HID + k0 + k] = f2bf(tile[k][n]);
  }
}

// ---------------- big GEMM: C[m][n] = epi( sum_k A[m][k]*Bp[n][k] )
// EPI 0: tanh(acc + bias[col])
// EPI 1: acc * (1 - bf2f(aux[row][col])^2)              (aux = raw h2)
// EPI 2: acc * (1 - tanh(x6[row]@W1[:,col] + b1[col])^2)  (recompute d1)
template<int EPI>
__global__ __launch_bounds__(256, 2) void gemm_bf16(
    const unsigned short* __restrict__ A,
    const unsigned short* __restrict__ Bp,
    unsigned short* __restrict__ C,
    const float* __restrict__ bias,
    const unsigned short* __restrict__ aux,
    const float* __restrict__ xall,
    const float* __restrict__ W1,
    const float* __restrict__ b1)
{
  __shared__ __align__(1024) char lds[65536];   // 2 x (A 16K + B 16K)
  const int t = threadIdx.x;
  const int w = t >> 6, l = t & 63;
  // bijective XCD swizzle: 2048 blocks, 8 XCDs -> each XCD owns 32 M-panels
  int bid = (int)blockIdx.x;
  int wg  = (bid & 7) * 256 + (bid >> 3);
  const int nt = wg & 7, mt = wg >> 3;
  const int r0 = mt << 7, n0 = nt << 7;
  const int wr = w >> 1, wc = w & 1;

  f32x4 acc[4][4] = {};
  const int lbase = (w << 2);

  // single lane-offset array shared by A and B staging (identical formula)
  int voff[4];
  #pragma unroll
  for (int i = 0; i < 4; ++i) {
    int o   = ((lbase + i) << 10) + (l << 4);
    int row = o >> 7;
    voff[i] = (row << 11) + ((o & 127) ^ ((row & 7) << 4));
  }
  const char* Abase = (const char*)A  + ((size_t)r0 << 11);
  const char* Bbase = (const char*)Bp + ((size_t)n0 << 11);

  // stage K-tile kt into slot with base `Ad` (compile-time pointer)
  auto STAGE = [&](char* Ad, int kt) {
    char* Bd = Ad + 16384;
    const char* Ak = Abase + kt * 128;
    const char* Bk = Bbase + kt * 128;
    #pragma unroll
    for (int i = 0; i < 4; ++i) {
      __builtin_amdgcn_global_load_lds((gconst_char*)(Ak + voff[i]), (lds_char*)(Ad + ((lbase + i) << 10)), 16, 0, 0);
      __builtin_amdgcn_global_load_lds((gconst_char*)(Bk + voff[i]), (lds_char*)(Bd + ((lbase + i) << 10)), 16, 0, 0);
    }
  };

  auto COMPUTE = [&](const char* As) {
    const char* Bs = As + 16384;
    #pragma unroll
    for (int kk = 0; kk < 2; ++kk) {
      short8 bfr[4];
      #pragma unroll
      for (int n = 0; n < 4; ++n) {
        int col = (wc << 6) + (n << 4) + (l & 15);
        int off = (col << 7) + ((l >> 4) << 4) + (kk << 6);
        off ^= ((col & 7) << 4);
        bfr[n] = *(const short8*)(Bs + off);
      }
      #pragma unroll
      for (int m = 0; m < 4; ++m) {
        int row = (wr << 6) + (m << 4) + (l & 15);
        int off = (row << 7) + ((l >> 4) << 4) + (kk << 6);
        off ^= ((row & 7) << 4);
        short8 af = *(const short8*)(As + off);
        #pragma unroll
        for (int n = 0; n < 4; ++n) {
          acc[m][n] = __builtin_amdgcn_mfma_f32_16x16x32_bf16(af, bfr[n], acc[m][n], 0, 0, 0);
        }
      }
      __builtin_amdgcn_sched_barrier(0);   // cap fragment live set at one kk
    }
  };

  char* L0 = lds;
  char* L1 = lds + 32768;

  // prologue: tile 0 into L0, drain, sync
  STAGE(L0, 0);
  asm volatile("s_waitcnt vmcnt(0)" ::: "memory");
  __builtin_amdgcn_s_barrier();

  // minimal 2-phase: STAGE(next) -> COMPUTE(cur) -> vmcnt(0) -> barrier.
  // Unrolled x2 so L0/L1 are compile-time bases (loop-invariant addressing).
  #pragma unroll 1
  for (int kt2 = 0; kt2 < 7; ++kt2) {
    STAGE(L1, 2 * kt2 + 1);
    COMPUTE(L0);
    asm volatile("s_waitcnt vmcnt(0)" ::: "memory");
    __builtin_amdgcn_s_barrier();
    STAGE(L0, 2 * kt2 + 2);
    COMPUTE(L1);
    asm volatile("s_waitcnt vmcnt(0)" ::: "memory");
    __builtin_amdgcn_s_barrier();
  }
  // kt = 14: stage tile 15, compute tile 14 (in L0)
  STAGE(L1, 15);
  COMPUTE(L0);
  asm volatile("s_waitcnt vmcnt(0)" ::: "memory");
  __builtin_amdgcn_s_barrier();
  // kt = 15
  COMPUTE(L1);
  __syncthreads();   // ds_reads retired before epilogue reuses LDS

  // epilogue: FULL unroll (compile-time acc indices -> AGPR, no scratch);
  // sched_barrier(0) after each m-chunk caps the accvgpr-read live range.
  char* Cs = lds;
  #pragma unroll
  for (int n = 0; n < 4; ++n) {
    const int colL = (wc << 6) + (n << 4) + (l & 15);
    const int gcol = n0 + colL;
    float bval = 0.f;
    float w1c[6];
    if (EPI == 0) bval = bias[gcol];
    if (EPI == 2) {
      bval = b1[gcol];
      #pragma unroll
      for (int k2 = 0; k2 < 6; ++k2) w1c[k2] = W1[k2 * HID + gcol];
    }
    #pragma unroll
    for (int m = 0; m < 4; ++m) {
      #pragma unroll
      for (int r = 0; r < 4; ++r) {
        const int rowL = (wr << 6) + (m << 4) + ((l >> 4) << 2) + r;
        float v = acc[m][n][r];
        if (EPI == 0) {
          v = tanh_fast(v + bval);
        } else if (EPI == 1) {
          float h = bf2f(aux[((size_t)(r0 + rowL) << 10) + gcol]);
          v *= (1.f - h * h);
        } else {
          const float* xr = xall + (size_t)(r0 + rowL) * 10;
          float z = bval;
          #pragma unroll
          for (int k2 = 0; k2 < 6; ++k2) z += xr[k2] * w1c[k2];
          float th = tanh_fast(z);
          v *= (1.f - th * th);
        }
        int so = (rowL << 8) + (colL << 1);
        so ^= ((rowL & 7) << 5);
        *(unsigned short*)(Cs + so) = f2bf(v);
      }
      __builtin_amdgcn_sched_barrier(0);   // cap live acc reads per chunk
    }
  }
  __syncthreads();
  #pragma unroll
  for (int j = 0; j < 8; ++j) {
    int o    = (j << 12) + (t << 4);
    int rowL = o >> 8;
    int ir   = o & 255;
    uint4 v = *(const uint4*)(Cs + ((rowL << 8) + (ir ^ ((rowL & 7) << 5))));
    *(uint4*)(C + ((size_t)(r0 + rowL) << 10) + n0 + (ir >> 1)) = v;
    if ((j & 1) == 1) __builtin_amdgcn_sched_barrier(0);  // cap store live set
  }
}

// ---------------- layer-1 forward: out = tanh(x6 @ W1 + b1), bf16
__global__ __launch_bounds__(256) void l1fwd(const float* __restrict__ x,
                                             const float* __restrict__ W1,
                                             const float* __restrict__ b1,
                                             unsigned short* __restrict__ out) {
  int idx = blockIdx.x * 256 + threadIdx.x;
  int r = idx >> 7;
  int n8 = (idx & 127) << 3;
  const float* xr = x + (size_t)r * 10;
  float xs[6];
  #pragma unroll
  for (int k = 0; k < 6; ++k) xs[k] = xr[k];
  float4 bb0 = *(const float4*)(b1 + n8), bb1 = *(const float4*)(b1 + n8 + 4);
  float z[8] = {bb0.x, bb0.y, bb0.z, bb0.w, bb1.x, bb1.y, bb1.z, bb1.w};
  #pragma unroll
  for (int k = 0; k < 6; ++k) {
    const float* wrow = W1 + (size_t)k * HID + n8;
    float4 wa = *(const float4*)wrow, wb = *(const float4*)(wrow + 4);
    z[0] += xs[k] * wa.x; z[1] += xs[k] * wa.y; z[2] += xs[k] * wa.z; z[3] += xs[k] * wa.w;
    z[4] += xs[k] * wb.x; z[5] += xs[k] * wb.y; z[6] += xs[k] * wb.z; z[7] += xs[k] * wb.w;
  }
  ushort8v o;
  #pragma unroll
  for (int j = 0; j < 8; ++j) o[j] = f2bf(tanh_fast(z[j]));
  *(ushort8v*)(out + (size_t)r * HID + n8) = o;
}

// ---------------- JVP layer-1: th1 = (tang @ W1) * (1 - tanh(x@W1+b1)^2)
__global__ __launch_bounds__(256) void l1t(const float* __restrict__ x,
                                           const float* __restrict__ outbuf, // tangent in cols 0..5
                                           const float* __restrict__ W1,
                                           const float* __restrict__ b1,
                                           unsigned short* __restrict__ P) {
  int idx = blockIdx.x * 256 + threadIdx.x;
  int r = idx >> 7;
  int n8 = (idx & 127) << 3;
  const float* xr = x + (size_t)r * 10;
  const float* tr = outbuf + (size_t)r * 10;
  float xs[6], ts[6];
  #pragma unroll
  for (int k = 0; k < 6; ++k) { xs[k] = xr[k]; ts[k] = tr[k]; }
  float4 bb0 = *(const float4*)(b1 + n8), bb1 = *(const float4*)(b1 + n8 + 4);
  float z[8] = {bb0.x, bb0.y, bb0.z, bb0.w, bb1.x, bb1.y, bb1.z, bb1.w};
  float tz[8] = {};
  #pragma unroll
  for (int k = 0; k < 6; ++k) {
    const float* wrow = W1 + (size_t)k * HID + n8;
    float4 wa = *(const float4*)wrow, wb = *(const float4*)(wrow + 4);
    z[0] += xs[k] * wa.x;  z[1] += xs[k] * wa.y;  z[2] += xs[k] * wa.z;  z[3] += xs[k] * wa.w;
    z[4] += xs[k] * wb.x;  z[5] += xs[k] * wb.y;  z[6] += xs[k] * wb.z;  z[7] += xs[k] * wb.w;
    tz[0] += ts[k] * wa.x; tz[1] += ts[k] * wa.y; tz[2] += ts[k] * wa.z; tz[3] += ts[k] * wa.w;
    tz[4] += ts[k] * wb.x; tz[5] += ts[k] * wb.y; tz[6] += ts[k] * wb.z; tz[7] += ts[k] * wb.w;
  }
  ushort8v o;
  #pragma unroll
  for (int j = 0; j < 8; ++j) {
    float th = tanh_fast(z[j]);
    o[j] = f2bf(tz[j] * (1.f - th * th));
  }
  *(ushort8v*)(P + (size_t)r * HID + n8) = o;
}

// ---------------- g2 = (gL @ MW3^T) * (1-h2^2), bf16  (K = 9, h2 raw)
__global__ __launch_bounds__(256) void k9bwd(const float* __restrict__ sGL,
                                             const float* __restrict__ MW3, // [1024][9]
                                             const unsigned short* __restrict__ h2,
                                             unsigned short* __restrict__ outp) {
  int idx = blockIdx.x * 256 + threadIdx.x;
  int r = idx >> 7;
  int n8 = (idx & 127) << 3;
  const float* g = sGL + (size_t)r * 9;
  float gl[9];
  #pragma unroll
  for (int j = 0; j < 9; ++j) gl[j] = g[j];
  ushort8v dv = *(const ushort8v*)(h2 + (size_t)r * HID + n8);
  ushort8v o;
  #pragma unroll
  for (int j = 0; j < 8; ++j) {
    const float* wr = MW3 + (size_t)(n8 + j) * 9;
    float s = 0.f;
    #pragma unroll
    for (int jj = 0; jj < 9; ++jj) s += gl[jj] * wr[jj];
    float h = bf2f(dv[j]);
    o[j] = f2bf(s * (1.f - h * h));
  }
  *(ushort8v*)(outp + (size_t)r * HID + n8) = o;
}

// ---------------- mapV: Rb := VW3[col] * (1 - Rb^2)
__global__ __launch_bounds__(256) void mapV(unsigned short* __restrict__ Rb,
                                            const float* __restrict__ VW3) {
  int idx = blockIdx.x * 256 + threadIdx.x;
  int r = idx >> 7;
  int n8 = (idx & 127) << 3;
  ushort8v v = *(ushort8v*)(Rb + (size_t)r * HID + n8);
  float4 w0 = *(const float4*)(VW3 + n8), w1 = *(const float4*)(VW3 + n8 + 4);
  float wv[8] = {w0.x, w0.y, w0.z, w0.w, w1.x, w1.y, w1.z, w1.w};
  #pragma unroll
  for (int j = 0; j < 8; ++j) { float f = bf2f(v[j]); v[j] = f2bf(wv[j] * (1.f - f * f)); }
  *(ushort8v*)(Rb + (size_t)r * HID + n8) = v;
}

// ---------------- skinny reductions (wave per row)
template<bool BIAS>
__global__ __launch_bounds__(256) void skinny9(const unsigned short* __restrict__ A,
                                               const float* __restrict__ W,  // [1024][9]
                                               const float* __restrict__ bias,
                                               float* __restrict__ out) {
  int wid = blockIdx.x * 4 + (threadIdx.x >> 6);
  int l = threadIdx.x & 63;
  const unsigned short* ar = A + (size_t)wid * HID;
  float acc[9] = {};
  for (int i = 0; i < 16; ++i) {
    int k = i * 64 + l;
    float a = bf2f(ar[k]);
    const float* wr = W + (size_t)k * 9;
    #pragma unroll
    for (int j = 0; j < 9; ++j) acc[j] += a * wr[j];
  }
  #pragma unroll
  for (int j = 0; j < 9; ++j) {
    float sv = acc[j];
    for (int d = 32; d; d >>= 1) sv += __shfl_down(sv, d);
    if (l == 0) out[(size_t)wid * 9 + j] = BIAS ? (sv + bias[j]) : sv;
  }
}
__global__ __launch_bounds__(256) void skinny6(const unsigned short* __restrict__ A,
                                               const float* __restrict__ W,  // [6][1024]
                                               float* __restrict__ out) {
  int wid = blockIdx.x * 4 + (threadIdx.x >> 6);
  int l = threadIdx.x & 63;
  const unsigned short* ar = A + (size_t)wid * HID;
  float acc[6] = {};
  for (int i = 0; i < 4; ++i) {
    int k = i * 256 + l * 4;
    ushort4v av = *(const ushort4v*)(ar + k);
    float a0 = bf2f(av[0]), a1 = bf2f(av[1]), a2 = bf2f(av[2]), a3 = bf2f(av[3]);
    #pragma unroll
    for (int j = 0; j < 6; ++j) {
      float4 wv = *(const float4*)(W + (size_t)j * HID + k);
      acc[j] += a0 * wv.x + a1 * wv.y + a2 * wv.z + a3 * wv.w;
    }
  }
  #pragma unroll
  for (int j = 0; j < 6; ++j) {
    float sv = acc[j];
    for (int d = 32; d; d >>= 1) sv += __shfl_down(sv, d);
    if (l == 0) out[(size_t)wid * 6 + j] = sv;
  }
}
__global__ __launch_bounds__(256) void skinny3(const unsigned short* __restrict__ A,
                                               const float* __restrict__ W,  // [1024][3]
                                               const float* __restrict__ bias,
                                               float* __restrict__ out) {
  int wid = blockIdx.x * 4 + (threadIdx.x >> 6);
  int l = threadIdx.x & 63;
  const unsigned short* ar = A + (size_t)wid * HID;
  float a0 = 0.f, a1 = 0.f, a2 = 0.f;
  for (int i = 0; i < 16; ++i) {
    int k = i * 64 + l;
    float a = bf2f(ar[k]);
    const float* wr = W + (size_t)k * 3;
    a0 += a * wr[0]; a1 += a * wr[1]; a2 += a * wr[2];
  }
  float acc[3] = {a0, a1, a2};
  #pragma unroll
  for (int j = 0; j < 3; ++j) {
    float sv = acc[j];
    for (int d = 32; d; d >>= 1) sv += __shfl_down(sv, d);
    if (l == 0) out[(size_t)wid * 3 + j] = sv + bias[j];
  }
}

// ---------------- per-row 3x3 algebra
__global__ __launch_bounds__(256) void rowA(const float* __restrict__ x,
                                            const float* __restrict__ sLvec,
                                            float* __restrict__ sP,
                                            float* __restrict__ sGL) {
  int r = blockIdx.x * 256 + threadIdx.x;
  const float* Lv = sLvec + (size_t)r * 9;
  float L[3][3];
  #pragma unroll
  for (int i = 0; i < 3; ++i)
    #pragma unroll
    for (int j = 0; j < 3; ++j) L[i][j] = Lv[3 * i + j];
  float a = 0.1f, b = 0.f, c = 0.f, d = 0.1f, e = 0.f, f = 0.1f;
  #pragma unroll
  for (int k = 0; k < 3; ++k) {
    a += L[0][k] * L[0][k]; b += L[0][k] * L[1][k]; c += L[0][k] * L[2][k];
    d += L[1][k] * L[1][k]; e += L[1][k] * L[2][k]; f += L[2][k] * L[2][k];
  }
  const float* xr = x + (size_t)r * 10;
  float q0 = xr[6], q1 = xr[7], q2 = xr[8];
  float c00 = d * f - e * e;
  float c01 = c * e - b * f;
  float c02 = b * e - c * d;
  float det = a * c00 + b * c01 + c * c02;
  float inv = 1.f / det;
  float i00 = c00 * inv, i01 = c01 * inv, i02 = c02 * inv;
  float i11 = (a * f - c * c) * inv;
  float i12 = (b * c - a * e) * inv;
  float i22 = (a * d - b * b) * inv;
  float p0 = i00 * q0 + i01 * q1 + i02 * q2;
  float p1 = i01 * q0 + i11 * q1 + i12 * q2;
  float p2 = i02 * q0 + i12 * q1 + i22 * q2;
  sP[(size_t)r * 3 + 0] = p0; sP[(size_t)r * 3 + 1] = p1; sP[(size_t)r * 3 + 2] = p2;
  float lt0 = p0 * L[0][0] + p1 * L[1][0] + p2 * L[2][0];
  float lt1 = p0 * L[0][1] + p1 * L[1][1] + p2 * L[2][1];
  float lt2 = p0 * L[0][2] + p1 * L[1][2] + p2 * L[2][2];
  float pp[3] = {p0, p1, p2}, lt[3] = {lt0, lt1, lt2};
  #pragma unroll
  for (int i = 0; i < 3; ++i)
    #pragma unroll
    for (int j = 0; j < 3; ++j) sGL[(size_t)r * 9 + 3 * i + j] = pp[i] * lt[j];
}

__global__ __launch_bounds__(256) void rowB(const float* __restrict__ x,
                                            const float* __restrict__ sGzM,
                                            const float* __restrict__ sGzV,
                                            const float* __restrict__ sGq,
                                            float* __restrict__ out,
                                            float* __restrict__ sDp) {
  int r = blockIdx.x * 256 + threadIdx.x;
  const float* xr = x + (size_t)r * 10;
  float u = xr[9];
  #pragma unroll
  for (int i = 0; i < 3; ++i) {
    float cosq = xr[i], sinq = xr[3 + i], qd = xr[6 + i];
    float dhc = sGzM[(size_t)r * 6 + i] + sGzV[(size_t)r * 6 + i];
    float dhs = sGzM[(size_t)r * 6 + 3 + i] + sGzV[(size_t)r * 6 + 3 + i];
    float F = sGq[(size_t)r * 3 + i] * u;
    float dq = qd;  // dHdp = M_inv @ p = q_dot exactly
    float dp = sinq * dhc - cosq * dhs + F;
    out[(size_t)r * 10 + i]     = -sinq * dq;
    out[(size_t)r * 10 + 3 + i] =  cosq * dq;
    sDp[(size_t)r * 3 + i] = dp;
  }
}

__global__ __launch_bounds__(256) void rowC(const float* __restrict__ sLvec,
                                            const float* __restrict__ sTL,
                                            const float* __restrict__ sP,
                                            const float* __restrict__ sDp,
                                            float* __restrict__ out) {
  int r = blockIdx.x * 256 + threadIdx.x;
  float L[3][3], T[3][3];
  #pragma unroll
  for (int i = 0; i < 3; ++i)
    #pragma unroll
    for (int j = 0; j < 3; ++j) {
      L[i][j] = sLvec[(size_t)r * 9 + 3 * i + j];
      T[i][j] = sTL[(size_t)r * 9 + 3 * i + j];
    }
  float Mi[3][3], dM[3][3];
  #pragma unroll
  for (int i = 0; i < 3; ++i) {
    #pragma unroll
    for (int j = 0; j < 3; ++j) {
      float s = 0.f, sd = 0.f;
      #pragma unroll
      for (int k = 0; k < 3; ++k) {
        s  += L[i][k] * L[j][k];
        sd += T[i][k] * L[j][k] + L[i][k] * T[j][k];
      }
      Mi[i][j] = s + (i == j ? 0.1f : 0.f);
      dM[i][j] = sd;
    }
  }
  float p[3], dp[3];
  #pragma unroll
  for (int i = 0; i < 3; ++i) { p[i] = sP[(size_t)r * 3 + i]; dp[i] = sDp[(size_t)r * 3 + i]; }
  #pragma unroll
  for (int i = 0; i < 3; ++i) {
    float s = 0.f;
    #pragma unroll
    for (int j = 0; j < 3; ++j) s += Mi[i][j] * dp[j] + dM[i][j] * p[j];
    out[(size_t)r * 10 + 6 + i] = s;
  }
  out[(size_t)r * 10 + 9] = 0.f;
}

// ---------------- host
extern "C" void kernel_launch(void* const* d_in, const int* in_sizes, int n_in,
                              void* d_out, int out_size, void* d_ws, size_t ws_size,
                              hipStream_t stream) {
  const float* x   = (const float*)d_in[1];
  const float* MW1 = (const float*)d_in[2];
  const float* Mb1 = (const float*)d_in[3];
  const float* MW2 = (const float*)d_in[4];
  const float* Mb2 = (const float*)d_in[5];
  const float* MW3 = (const float*)d_in[6];
  const float* Mb3 = (const float*)d_in[7];
  const float* VW1 = (const float*)d_in[8];
  const float* Vb1 = (const float*)d_in[9];
  const float* VW2 = (const float*)d_in[10];
  const float* Vb2 = (const float*)d_in[11];
  const float* VW3 = (const float*)d_in[12];
  const float* GW1 = (const float*)d_in[14];
  const float* Gb1 = (const float*)d_in[15];
  const float* GW2 = (const float*)d_in[16];
  const float* Gb2 = (const float*)d_in[17];
  const float* GW3 = (const float*)d_in[18];
  const float* Gb3 = (const float*)d_in[19];
  float* out = (float*)d_out;
  char* ws = (char*)d_ws;

  const size_t PK  = (size_t)HID * HID * 2;
  const size_t BUF = (size_t)BS * HID * 2;
  const size_t NEED = 5 * PK + 3 * BUF + (size_t)BS * 48 * 4;
  if (ws_size < NEED) return;  // ws too small: fail visibly (output untouched)

  unsigned short* MW2p  = (unsigned short*)(ws + 0 * PK);
  unsigned short* MW2tp = (unsigned short*)(ws + 1 * PK);
  unsigned short* VW2p  = (unsigned short*)(ws + 2 * PK);
  unsigned short* VW2tp = (unsigned short*)(ws + 3 * PK);
  unsigned short* GW2p  = (unsigned short*)(ws + 4 * PK);
  unsigned short* P = (unsigned short*)(ws + 5 * PK);
  unsigned short* Q = (unsigned short*)(ws + 5 * PK + BUF);
  unsigned short* R = (unsigned short*)(ws + 5 * PK + 2 * BUF);
  char* s = ws + 5 * PK + 3 * BUF;
  float* sLvec = (float*)(s);
  float* sP    = (float*)(s + (size_t)BS *  9 * 4);
  float* sGL   = (float*)(s + (size_t)BS * 12 * 4);
  float* sGzM  = (float*)(s + (size_t)BS * 21 * 4);
  float* sGzV  = (float*)(s + (size_t)BS * 27 * 4);
  float* sGq   = (float*)(s + (size_t)BS * 33 * 4);
  float* sDp   = (float*)(s + (size_t)BS * 36 * 4);
  float* sTL   = (float*)(s + (size_t)BS * 39 * 4);

  dim3 B(256);
  const int G_GEMM = 2048;          // 256 mt x 8 nt
  const int G_EW   = BS * 128 / 256; // 16384
  const int G_SK   = BS / 4;         // 8192
  const int G_ROW  = BS / 256;       // 128

  // weight packing
  pack_w<<<256, B, 0, stream>>>(MW2, MW2p, MW2tp);
  pack_w<<<256, B, 0, stream>>>(VW2, VW2p, VW2tp);
  pack_w<<<256, B, 0, stream>>>(GW2, GW2p, nullptr);

  // M forward
  l1fwd<<<G_EW, B, 0, stream>>>(x, MW1, Mb1, P);                                  // h1M
  gemm_bf16<0><<<G_GEMM, B, 0, stream>>>(P, MW2p, Q, Mb2, nullptr, nullptr, nullptr, nullptr); // h2M (raw)
  skinny9<true><<<G_SK, B, 0, stream>>>(Q, MW3, Mb3, sLvec);                      // Lvec
  rowA<<<G_ROW, B, 0, stream>>>(x, sLvec, sP, sGL);                               // p, gL

  // M backward -> gzM  (d2 computed inline from raw h2)
  k9bwd<<<G_EW, B, 0, stream>>>(sGL, MW3, Q, P);                                  // g2
  gemm_bf16<2><<<G_GEMM, B, 0, stream>>>(P, MW2tp, R, nullptr, nullptr, x, MW1, Mb1); // g1
  skinny6<<<G_SK, B, 0, stream>>>(R, MW1, sGzM);

  // G forward -> g_q
  l1fwd<<<G_EW, B, 0, stream>>>(x, GW1, Gb1, P);
  gemm_bf16<0><<<G_GEMM, B, 0, stream>>>(P, GW2p, R, Gb2, nullptr, nullptr, nullptr, nullptr);
  skinny3<<<G_SK, B, 0, stream>>>(R, GW3, Gb3, sGq);

  // V backward -> gzV
  l1fwd<<<G_EW, B, 0, stream>>>(x, VW1, Vb1, P);                                  // vh1
  gemm_bf16<0><<<G_GEMM, B, 0, stream>>>(P, VW2p, R, Vb2, nullptr, nullptr, nullptr, nullptr); // vh2
  mapV<<<G_EW, B, 0, stream>>>(R, VW3);                                           // gv2
  gemm_bf16<2><<<G_GEMM, B, 0, stream>>>(R, VW2tp, P, nullptr, nullptr, x, VW1, Vb1); // gv1
  skinny6<<<G_SK, B, 0, stream>>>(P, VW1, sGzV);

  // assemble tangent, dp; write out[:, 0:6]
  rowB<<<G_ROW, B, 0, stream>>>(x, sGzM, sGzV, sGq, out, sDp);

  // JVP through M-net (aux = raw h2; EPI1 computes 1-h2^2 inline)
  l1t<<<G_EW, B, 0, stream>>>(x, out, MW1, Mb1, P);                               // th1
  gemm_bf16<1><<<G_GEMM, B, 0, stream>>>(P, MW2p, R, nullptr, Q, nullptr, nullptr, nullptr); // th2
  skinny9<false><<<G_SK, B, 0, stream>>>(R, MW3, nullptr, sTL);                   // tLvec

  // final: ddq; write out[:, 6:10]
  rowC<<<G_ROW, B, 0, stream>>>(sLvec, sTL, sP, sDp, out);
}

// Round 14
// 1020.954 us; speedup vs baseline: 1.3809x; 1.0072x over previous
//
#include <hip/hip_runtime.h>

// HNN structure embed (N=3, HID=1024, bs=32768).
// GEMMs: bf16 MFMA 16x16x32, 128x128x64 tiles, 2-slot LDS ring (64 KB),
// minimal 2-phase loop, __launch_bounds__(256,2). R14: R13's register diet
// (EPI2 removed, n-pair fragments, inline voff) WITHOUT the 4th buffer that
// overflowed ws (R13 failed on the ws guard). EPI1 aux is read exactly over
// the block's own output tile before any store -> in-place C==aux is safe,
// so h1 lives in P and g1 overwrites it in place. NEED back to 208 MB.
// Per-row 3x3 algebra in f32. dHdp == q_dot (exact). V layer-3 fwd skipped.

#define HID 1024
#define BS  32768

typedef __attribute__((ext_vector_type(8))) short short8;
typedef __attribute__((ext_vector_type(4))) float f32x4;
typedef __attribute__((ext_vector_type(8))) unsigned short ushort8v;
typedef __attribute__((ext_vector_type(4))) unsigned short ushort4v;

typedef __attribute__((address_space(1))) const char gconst_char;
typedef __attribute__((address_space(3))) char lds_char;

__device__ __forceinline__ unsigned short f2bf(float f) {
  unsigned int u = __builtin_bit_cast(unsigned int, f);
  u += 0x7fffu + ((u >> 16) & 1u);   // RNE
  return (unsigned short)(u >> 16);
}
__device__ __forceinline__ float bf2f(unsigned short s) {
  unsigned int u = ((unsigned int)s) << 16;
  return __builtin_bit_cast(float, u);
}
__device__ __forceinline__ float tanh_fast(float x) {
  float e = __builtin_amdgcn_exp2f(x * 2.885390081777927f); // e^(2x)
  return 1.f - 2.f * __builtin_amdgcn_rcpf(e + 1.f);
}

// ---------------- weight packing: pT[n][k]=bf16(W[k][n]); pC[n][k]=bf16(W[n][k])
__global__ __launch_bounds__(256) void pack_w(const float* __restrict__ W,
                                              unsigned short* __restrict__ pT,
                                              unsigned short* __restrict__ pC) {
  __shared__ float tile[64][65];
  int b = blockIdx.x;
  int k0 = (b >> 4) << 6;
  int n0 = (b & 15) << 6;
  int t = threadIdx.x;
  for (int i = 0; i < 16; ++i) {
    int idx = i * 256 + t;
    int r = idx >> 6, c = idx & 63;
    tile[r][c] = W[(size_t)(k0 + r) * HID + n0 + c];
  }
  if (pC) {
    for (int i = 0; i < 16; ++i) {
      int idx = i * 256 + t;
      int r = idx >> 6, c = idx & 63;
      pC[(size_t)(n0 + r) * HID + k0 + c] = f2bf(W[(size_t)(n0 + r) * HID + k0 + c]);
    }
  }
  __syncthreads();
  for (int i = 0; i < 16; ++i) {
    int idx = i * 256 + t;
    int n = idx >> 6, k = idx & 63;
    pT[(size_t)(n0 + n) * HID + k0 + k] = f2bf(tile[k][n]);
  }
}

// ---------------- big GEMM: C[m][n] = epi( sum_k A[m][k]*Bp[n][k] )
// EPI 0: tanh(acc + bias[col])
// EPI 1: acc * (1 - bf2f(aux[row][col])^2)   (aux = bf16 tanh activation;
//        aux may alias C: each block reads only its own output tile, and all
//        reads complete before the post-barrier stores)
template<int EPI>
__global__ __launch_bounds__(256, 2) void gemm_bf16(
    const unsigned short* __restrict__ A,
    const unsigned short* __restrict__ Bp,
    unsigned short* __restrict__ C,
    const float* __restrict__ bias,
    const unsigned short* __restrict__ aux)
{
  __shared__ __align__(1024) char lds[65536];   // 2 x (A 16K + B 16K)
  const int t = threadIdx.x;
  const int w = t >> 6, l = t & 63;
  // bijective XCD swizzle: 2048 blocks, 8 XCDs -> each XCD owns 32 M-panels
  int bid = (int)blockIdx.x;
  int wg  = (bid & 7) * 256 + (bid >> 3);
  const int nt = wg & 7, mt = wg >> 3;
  const int r0 = mt << 7, n0 = nt << 7;
  const int wr = w >> 1, wc = w & 1;

  f32x4 acc[4][4] = {};
  const int lbase = (w << 2);

  const char* Abase = (const char*)A  + ((size_t)r0 << 11);
  const char* Bbase = (const char*)Bp + ((size_t)n0 << 11);

  // stage K-tile kt into slot with base `Ad`; lane offset recomputed inline
  auto STAGE = [&](char* Ad, int kt) {
    char* Bd = Ad + 16384;
    const char* Ak = Abase + kt * 128;
    const char* Bk = Bbase + kt * 128;
    #pragma unroll
    for (int i = 0; i < 4; ++i) {
      int o   = ((lbase + i) << 10) + (l << 4);
      int row = o >> 7;
      int vo  = (row << 11) + ((o & 127) ^ ((row & 7) << 4));   // inv swizzle on SOURCE
      __builtin_amdgcn_global_load_lds((gconst_char*)(Ak + vo), (lds_char*)(Ad + ((lbase + i) << 10)), 16, 0, 0);
      __builtin_amdgcn_global_load_lds((gconst_char*)(Bk + vo), (lds_char*)(Bd + ((lbase + i) << 10)), 16, 0, 0);
    }
  };

  auto COMPUTE = [&](const char* As) {
    const char* Bs = As + 16384;
    #pragma unroll
    for (int kk = 0; kk < 2; ++kk) {
      #pragma unroll
      for (int np = 0; np < 2; ++np) {
        int col = (wc << 6) + ((np << 1) << 4) + (l & 15);
        int boff = (col << 7) + ((l >> 4) << 4) + (kk << 6);
        boff ^= ((col & 7) << 4);
        short8 b0 = *(const short8*)(Bs + boff);
        short8 b1 = *(const short8*)(Bs + boff + 2048);   // col+16: XOR part unchanged
        #pragma unroll
        for (int m = 0; m < 4; ++m) {
          int row = (wr << 6) + (m << 4) + (l & 15);
          int aoff = (row << 7) + ((l >> 4) << 4) + (kk << 6);
          aoff ^= ((row & 7) << 4);
          short8 af = *(const short8*)(As + aoff);
          acc[m][(np << 1)]     = __builtin_amdgcn_mfma_f32_16x16x32_bf16(af, b0, acc[m][(np << 1)], 0, 0, 0);
          acc[m][(np << 1) + 1] = __builtin_amdgcn_mfma_f32_16x16x32_bf16(af, b1, acc[m][(np << 1) + 1], 0, 0, 0);
        }
        __builtin_amdgcn_sched_barrier(0);   // cap fragment live set per n-pair
      }
    }
  };

  char* L0 = lds;
  char* L1 = lds + 32768;

  // prologue: tile 0 into L0, drain, sync
  STAGE(L0, 0);
  asm volatile("s_waitcnt vmcnt(0)" ::: "memory");
  __builtin_amdgcn_s_barrier();

  // minimal 2-phase: STAGE(next) -> COMPUTE(cur) -> vmcnt(0) -> barrier.
  #pragma unroll 1
  for (int kt2 = 0; kt2 < 7; ++kt2) {
    STAGE(L1, 2 * kt2 + 1);
    COMPUTE(L0);
    asm volatile("s_waitcnt vmcnt(0)" ::: "memory");
    __builtin_amdgcn_s_barrier();
    STAGE(L0, 2 * kt2 + 2);
    COMPUTE(L1);
    asm volatile("s_waitcnt vmcnt(0)" ::: "memory");
    __builtin_amdgcn_s_barrier();
  }
  STAGE(L1, 15);
  COMPUTE(L0);
  asm volatile("s_waitcnt vmcnt(0)" ::: "memory");
  __builtin_amdgcn_s_barrier();
  COMPUTE(L1);
  __syncthreads();   // ds_reads retired before epilogue reuses LDS

  // epilogue: FULL unroll (compile-time acc indices -> AGPR, no scratch);
  // sched_barrier(0) after each m-chunk caps the accvgpr-read live range.
  char* Cs = lds;
  #pragma unroll
  for (int n = 0; n < 4; ++n) {
    const int colL = (wc << 6) + (n << 4) + (l & 15);
    const int gcol = n0 + colL;
    float bval = 0.f;
    if (EPI == 0) bval = bias[gcol];
    #pragma unroll
    for (int m = 0; m < 4; ++m) {
      #pragma unroll
      for (int r = 0; r < 4; ++r) {
        const int rowL = (wr << 6) + (m << 4) + ((l >> 4) << 2) + r;
        float v = acc[m][n][r];
        if (EPI == 0) {
          v = tanh_fast(v + bval);
        } else {
          float h = bf2f(aux[((size_t)(r0 + rowL) << 10) + gcol]);
          v *= (1.f - h * h);
        }
        int so = (rowL << 8) + (colL << 1);
        so ^= ((rowL & 7) << 5);
        *(unsigned short*)(Cs + so) = f2bf(v);
      }
      __builtin_amdgcn_sched_barrier(0);   // cap live acc reads per chunk
    }
  }
  __syncthreads();   // all aux reads done; stores below (C may alias aux)
  #pragma unroll
  for (int j = 0; j < 8; ++j) {
    int o    = (j << 12) + (t << 4);
    int rowL = o >> 8;
    int ir   = o & 255;
    uint4 v = *(const uint4*)(Cs + ((rowL << 8) + (ir ^ ((rowL & 7) << 5))));
    *(uint4*)(C + ((size_t)(r0 + rowL) << 10) + n0 + (ir >> 1)) = v;
    __builtin_amdgcn_sched_barrier(0);  // cap store live set
  }
}

// ---------------- layer-1 forward: out = tanh(x6 @ W1 + b1), bf16
__global__ __launch_bounds__(256) void l1fwd(const float* __restrict__ x,
                                             const float* __restrict__ W1,
                                             const float* __restrict__ b1,
                                             unsigned short* __restrict__ out) {
  int idx = blockIdx.x * 256 + threadIdx.x;
  int r = idx >> 7;
  int n8 = (idx & 127) << 3;
  const float* xr = x + (size_t)r * 10;
  float xs[6];
  #pragma unroll
  for (int k = 0; k < 6; ++k) xs[k] = xr[k];
  float4 bb0 = *(const float4*)(b1 + n8), bb1 = *(const float4*)(b1 + n8 + 4);
  float z[8] = {bb0.x, bb0.y, bb0.z, bb0.w, bb1.x, bb1.y, bb1.z, bb1.w};
  #pragma unroll
  for (int k = 0; k < 6; ++k) {
    const float* wrow = W1 + (size_t)k * HID + n8;
    float4 wa = *(const float4*)wrow, wb = *(const float4*)(wrow + 4);
    z[0] += xs[k] * wa.x; z[1] += xs[k] * wa.y; z[2] += xs[k] * wa.z; z[3] += xs[k] * wa.w;
    z[4] += xs[k] * wb.x; z[5] += xs[k] * wb.y; z[6] += xs[k] * wb.z; z[7] += xs[k] * wb.w;
  }
  ushort8v o;
  #pragma unroll
  for (int j = 0; j < 8; ++j) o[j] = f2bf(tanh_fast(z[j]));
  *(ushort8v*)(out + (size_t)r * HID + n8) = o;
}

// ---------------- JVP layer-1: th1 = (tang @ W1) * (1 - tanh(x@W1+b1)^2)
__global__ __launch_bounds__(256) void l1t(const float* __restrict__ x,
                                           const float* __restrict__ outbuf, // tangent in cols 0..5
                                           const float* __restrict__ W1,
                                           const float* __restrict__ b1,
                                           unsigned short* __restrict__ P) {
  int idx = blockIdx.x * 256 + threadIdx.x;
  int r = idx >> 7;
  int n8 = (idx & 127) << 3;
  const float* xr = x + (size_t)r * 10;
  const float* tr = outbuf + (size_t)r * 10;
  float xs[6], ts[6];
  #pragma unroll
  for (int k = 0; k < 6; ++k) { xs[k] = xr[k]; ts[k] = tr[k]; }
  float4 bb0 = *(const float4*)(b1 + n8), bb1 = *(const float4*)(b1 + n8 + 4);
  float z[8] = {bb0.x, bb0.y, bb0.z, bb0.w, bb1.x, bb1.y, bb1.z, bb1.w};
  float tz[8] = {};
  #pragma unroll
  for (int k = 0; k < 6; ++k) {
    const float* wrow = W1 + (size_t)k * HID + n8;
    float4 wa = *(const float4*)wrow, wb = *(const float4*)(wrow + 4);
    z[0] += xs[k] * wa.x;  z[1] += xs[k] * wa.y;  z[2] += xs[k] * wa.z;  z[3] += xs[k] * wa.w;
    z[4] += xs[k] * wb.x;  z[5] += xs[k] * wb.y;  z[6] += xs[k] * wb.z;  z[7] += xs[k] * wb.w;
    tz[0] += ts[k] * wa.x; tz[1] += ts[k] * wa.y; tz[2] += ts[k] * wa.z; tz[3] += ts[k] * wa.w;
    tz[4] += ts[k] * wb.x; tz[5] += ts[k] * wb.y; tz[6] += ts[k] * wb.z; tz[7] += ts[k] * wb.w;
  }
  ushort8v o;
  #pragma unroll
  for (int j = 0; j < 8; ++j) {
    float th = tanh_fast(z[j]);
    o[j] = f2bf(tz[j] * (1.f - th * th));
  }
  *(ushort8v*)(P + (size_t)r * HID + n8) = o;
}

// ---------------- g2 = (gL @ MW3^T) * (1-h2^2), bf16  (K = 9, h2 raw)
__global__ __launch_bounds__(256) void k9bwd(const float* __restrict__ sGL,
                                             const float* __restrict__ MW3, // [1024][9]
                                             const unsigned short* __restrict__ h2,
                                             unsigned short* __restrict__ outp) {
  int idx = blockIdx.x * 256 + threadIdx.x;
  int r = idx >> 7;
  int n8 = (idx & 127) << 3;
  const float* g = sGL + (size_t)r * 9;
  float gl[9];
  #pragma unroll
  for (int j = 0; j < 9; ++j) gl[j] = g[j];
  ushort8v dv = *(const ushort8v*)(h2 + (size_t)r * HID + n8);
  ushort8v o;
  #pragma unroll
  for (int j = 0; j < 8; ++j) {
    const float* wr = MW3 + (size_t)(n8 + j) * 9;
    float s = 0.f;
    #pragma unroll
    for (int jj = 0; jj < 9; ++jj) s += gl[jj] * wr[jj];
    float h = bf2f(dv[j]);
    o[j] = f2bf(s * (1.f - h * h));
  }
  *(ushort8v*)(outp + (size_t)r * HID + n8) = o;
}

// ---------------- mapV: Rb := VW3[col] * (1 - Rb^2)
__global__ __launch_bounds__(256) void mapV(unsigned short* __restrict__ Rb,
                                            const float* __restrict__ VW3) {
  int idx = blockIdx.x * 256 + threadIdx.x;
  int r = idx >> 7;
  int n8 = (idx & 127) << 3;
  ushort8v v = *(ushort8v*)(Rb + (size_t)r * HID + n8);
  float4 w0 = *(const float4*)(VW3 + n8), w1 = *(const float4*)(VW3 + n8 + 4);
  float wv[8] = {w0.x, w0.y, w0.z, w0.w, w1.x, w1.y, w1.z, w1.w};
  #pragma unroll
  for (int j = 0; j < 8; ++j) { float f = bf2f(v[j]); v[j] = f2bf(wv[j] * (1.f - f * f)); }
  *(ushort8v*)(Rb + (size_t)r * HID + n8) = v;
}

// ---------------- skinny reductions (wave per row)
template<bool BIAS>
__global__ __launch_bounds__(256) void skinny9(const unsigned short* __restrict__ A,
                                               const float* __restrict__ W,  // [1024][9]
                                               const float* __restrict__ bias,
                                               float* __restrict__ out) {
  int wid = blockIdx.x * 4 + (threadIdx.x >> 6);
  int l = threadIdx.x & 63;
  const unsigned short* ar = A + (size_t)wid * HID;
  float acc[9] = {};
  for (int i = 0; i < 16; ++i) {
    int k = i * 64 + l;
    float a = bf2f(ar[k]);
    const float* wr = W + (size_t)k * 9;
    #pragma unroll
    for (int j = 0; j < 9; ++j) acc[j] += a * wr[j];
  }
  #pragma unroll
  for (int j = 0; j < 9; ++j) {
    float sv = acc[j];
    for (int d = 32; d; d >>= 1) sv += __shfl_down(sv, d);
    if (l == 0) out[(size_t)wid * 9 + j] = BIAS ? (sv + bias[j]) : sv;
  }
}
__global__ __launch_bounds__(256) void skinny6(const unsigned short* __restrict__ A,
                                               const float* __restrict__ W,  // [6][1024]
                                               float* __restrict__ out) {
  int wid = blockIdx.x * 4 + (threadIdx.x >> 6);
  int l = threadIdx.x & 63;
  const unsigned short* ar = A + (size_t)wid * HID;
  float acc[6] = {};
  for (int i = 0; i < 4; ++i) {
    int k = i * 256 + l * 4;
    ushort4v av = *(const ushort4v*)(ar + k);
    float a0 = bf2f(av[0]), a1 = bf2f(av[1]), a2 = bf2f(av[2]), a3 = bf2f(av[3]);
    #pragma unroll
    for (int j = 0; j < 6; ++j) {
      float4 wv = *(const float4*)(W + (size_t)j * HID + k);
      acc[j] += a0 * wv.x + a1 * wv.y + a2 * wv.z + a3 * wv.w;
    }
  }
  #pragma unroll
  for (int j = 0; j < 6; ++j) {
    float sv = acc[j];
    for (int d = 32; d; d >>= 1) sv += __shfl_down(sv, d);
    if (l == 0) out[(size_t)wid * 6 + j] = sv;
  }
}
__global__ __launch_bounds__(256) void skinny3(const unsigned short* __restrict__ A,
                                               const float* __restrict__ W,  // [1024][3]
                                               const float* __restrict__ bias,
                                               float* __restrict__ out) {
  int wid = blockIdx.x * 4 + (threadIdx.x >> 6);
  int l = threadIdx.x & 63;
  const unsigned short* ar = A + (size_t)wid * HID;
  float a0 = 0.f, a1 = 0.f, a2 = 0.f;
  for (int i = 0; i < 16; ++i) {
    int k = i * 64 + l;
    float a = bf2f(ar[k]);
    const float* wr = W + (size_t)k * 3;
    a0 += a * wr[0]; a1 += a * wr[1]; a2 += a * wr[2];
  }
  float acc[3] = {a0, a1, a2};
  #pragma unroll
  for (int j = 0; j < 3; ++j) {
    float sv = acc[j];
    for (int d = 32; d; d >>= 1) sv += __shfl_down(sv, d);
    if (l == 0) out[(size_t)wid * 3 + j] = sv + bias[j];
  }
}

// ---------------- per-row 3x3 algebra
__global__ __launch_bounds__(256) void rowA(const float* __restrict__ x,
                                            const float* __restrict__ sLvec,
                                            float* __restrict__ sP,
                                            float* __restrict__ sGL) {
  int r = blockIdx.x * 256 + threadIdx.x;
  const float* Lv = sLvec + (size_t)r * 9;
  float L[3][3];
  #pragma unroll
  for (int i = 0; i < 3; ++i)
    #pragma unroll
    for (int j = 0; j < 3; ++j) L[i][j] = Lv[3 * i + j];
  float a = 0.1f, b = 0.f, c = 0.f, d = 0.1f, e = 0.f, f = 0.1f;
  #pragma unroll
  for (int k = 0; k < 3; ++k) {
    a += L[0][k] * L[0][k]; b += L[0][k] * L[1][k]; c += L[0][k] * L[2][k];
    d += L[1][k] * L[1][k]; e += L[1][k] * L[2][k]; f += L[2][k] * L[2][k];
  }
  const float* xr = x + (size_t)r * 10;
  float q0 = xr[6], q1 = xr[7], q2 = xr[8];
  float c00 = d * f - e * e;
  float c01 = c * e - b * f;
  float c02 = b * e - c * d;
  float det = a * c00 + b * c01 + c * c02;
  float inv = 1.f / det;
  float i00 = c00 * inv, i01 = c01 * inv, i02 = c02 * inv;
  float i11 = (a * f - c * c) * inv;
  float i12 = (b * c - a * e) * inv;
  float i22 = (a * d - b * b) * inv;
  float p0 = i00 * q0 + i01 * q1 + i02 * q2;
  float p1 = i01 * q0 + i11 * q1 + i12 * q2;
  float p2 = i02 * q0 + i12 * q1 + i22 * q2;
  sP[(size_t)r * 3 + 0] = p0; sP[(size_t)r * 3 + 1] = p1; sP[(size_t)r * 3 + 2] = p2;
  float lt0 = p0 * L[0][0] + p1 * L[1][0] + p2 * L[2][0];
  float lt1 = p0 * L[0][1] + p1 * L[1][1] + p2 * L[2][1];
  float lt2 = p0 * L[0][2] + p1 * L[1][2] + p2 * L[2][2];
  float pp[3] = {p0, p1, p2}, lt[3] = {lt0, lt1, lt2};
  #pragma unroll
  for (int i = 0; i < 3; ++i)
    #pragma unroll
    for (int j = 0; j < 3; ++j) sGL[(size_t)r * 9 + 3 * i + j] = pp[i] * lt[j];
}

__global__ __launch_bounds__(256) void rowB(const float* __restrict__ x,
                                            const float* __restrict__ sGzM,
                                            const float* __restrict__ sGzV,
                                            const float* __restrict__ sGq,
                                            float* __restrict__ out,
                                            float* __restrict__ sDp) {
  int r = blockIdx.x * 256 + threadIdx.x;
  const float* xr = x + (size_t)r * 10;
  float u = xr[9];
  #pragma unroll
  for (int i = 0; i < 3; ++i) {
    float cosq = xr[i], sinq = xr[3 + i], qd = xr[6 + i];
    float dhc = sGzM[(size_t)r * 6 + i] + sGzV[(size_t)r * 6 + i];
    float dhs = sGzM[(size_t)r * 6 + 3 + i] + sGzV[(size_t)r * 6 + 3 + i];
    float F = sGq[(size_t)r * 3 + i] * u;
    float dq = qd;  // dHdp = M_inv @ p = q_dot exactly
    float dp = sinq * dhc - cosq * dhs + F;
    out[(size_t)r * 10 + i]     = -sinq * dq;
    out[(size_t)r * 10 + 3 + i] =  cosq * dq;
    sDp[(size_t)r * 3 + i] = dp;
  }
}

__global__ __launch_bounds__(256) void rowC(const float* __restrict__ sLvec,
                                            const float* __restrict__ sTL,
                                            const float* __restrict__ sP,
                                            const float* __restrict__ sDp,
                                            float* __restrict__ out) {
  int r = blockIdx.x * 256 + threadIdx.x;
  float L[3][3], T[3][3];
  #pragma unroll
  for (int i = 0; i < 3; ++i)
    #pragma unroll
    for (int j = 0; j < 3; ++j) {
      L[i][j] = sLvec[(size_t)r * 9 + 3 * i + j];
      T[i][j] = sTL[(size_t)r * 9 + 3 * i + j];
    }
  float Mi[3][3], dM[3][3];
  #pragma unroll
  for (int i = 0; i < 3; ++i) {
    #pragma unroll
    for (int j = 0; j < 3; ++j) {
      float s = 0.f, sd = 0.f;
      #pragma unroll
      for (int k = 0; k < 3; ++k) {
        s  += L[i][k] * L[j][k];
        sd += T[i][k] * L[j][k] + L[i][k] * T[j][k];
      }
      Mi[i][j] = s + (i == j ? 0.1f : 0.f);
      dM[i][j] = sd;
    }
  }
  float p[3], dp[3];
  #pragma unroll
  for (int i = 0; i < 3; ++i) { p[i] = sP[(size_t)r * 3 + i]; dp[i] = sDp[(size_t)r * 3 + i]; }
  #pragma unroll
  for (int i = 0; i < 3; ++i) {
    float s = 0.f;
    #pragma unroll
    for (int j = 0; j < 3; ++j) s += Mi[i][j] * dp[j] + dM[i][j] * p[j];
    out[(size_t)r * 10 + 6 + i] = s;
  }
  out[(size_t)r * 10 + 9] = 0.f;
}

// ---------------- host
extern "C" void kernel_launch(void* const* d_in, const int* in_sizes, int n_in,
                              void* d_out, int out_size, void* d_ws, size_t ws_size,
                              hipStream_t stream) {
  const float* x   = (const float*)d_in[1];
  const float* MW1 = (const float*)d_in[2];
  const float* Mb1 = (const float*)d_in[3];
  const float* MW2 = (const float*)d_in[4];
  const float* Mb2 = (const float*)d_in[5];
  const float* MW3 = (const float*)d_in[6];
  const float* Mb3 = (const float*)d_in[7];
  const float* VW1 = (const float*)d_in[8];
  const float* Vb1 = (const float*)d_in[9];
  const float* VW2 = (const float*)d_in[10];
  const float* Vb2 = (const float*)d_in[11];
  const float* VW3 = (const float*)d_in[12];
  const float* GW1 = (const float*)d_in[14];
  const float* Gb1 = (const float*)d_in[15];
  const float* GW2 = (const float*)d_in[16];
  const float* Gb2 = (const float*)d_in[17];
  const float* GW3 = (const float*)d_in[18];
  const float* Gb3 = (const float*)d_in[19];
  float* out = (float*)d_out;
  char* ws = (char*)d_ws;

  const size_t PK  = (size_t)HID * HID * 2;
  const size_t BUF = (size_t)BS * HID * 2;
  const size_t NEED = 5 * PK + 3 * BUF + (size_t)BS * 48 * 4;
  if (ws_size < NEED) return;  // ws too small: fail visibly (output untouched)

  unsigned short* MW2p  = (unsigned short*)(ws + 0 * PK);
  unsigned short* MW2tp = (unsigned short*)(ws + 1 * PK);
  unsigned short* VW2p  = (unsigned short*)(ws + 2 * PK);
  unsigned short* VW2tp = (unsigned short*)(ws + 3 * PK);
  unsigned short* GW2p  = (unsigned short*)(ws + 4 * PK);
  unsigned short* P = (unsigned short*)(ws + 5 * PK);
  unsigned short* Q = (unsigned short*)(ws + 5 * PK + BUF);
  unsigned short* R = (unsigned short*)(ws + 5 * PK + 2 * BUF);
  char* s = ws + 5 * PK + 3 * BUF;
  float* sLvec = (float*)(s);
  float* sP    = (float*)(s + (size_t)BS *  9 * 4);
  float* sGL   = (float*)(s + (size_t)BS * 12 * 4);
  float* sGzM  = (float*)(s + (size_t)BS * 21 * 4);
  float* sGzV  = (float*)(s + (size_t)BS * 27 * 4);
  float* sGq   = (float*)(s + (size_t)BS * 33 * 4);
  float* sDp   = (float*)(s + (size_t)BS * 36 * 4);
  float* sTL   = (float*)(s + (size_t)BS * 39 * 4);

  dim3 B(256);
  const int G_GEMM = 2048;          // 256 mt x 8 nt
  const int G_EW   = BS * 128 / 256; // 16384
  const int G_SK   = BS / 4;         // 8192
  const int G_ROW  = BS / 256;       // 128

  // weight packing
  pack_w<<<256, B, 0, stream>>>(MW2, MW2p, MW2tp);
  pack_w<<<256, B, 0, stream>>>(VW2, VW2p, VW2tp);
  pack_w<<<256, B, 0, stream>>>(GW2, GW2p, nullptr);

  // M forward (h1M stays in P until M-backward consumes it)
  l1fwd<<<G_EW, B, 0, stream>>>(x, MW1, Mb1, P);                                  // h1M
  gemm_bf16<0><<<G_GEMM, B, 0, stream>>>(P, MW2p, Q, Mb2, nullptr);               // h2M (raw)
  skinny9<true><<<G_SK, B, 0, stream>>>(Q, MW3, Mb3, sLvec);                      // Lvec
  rowA<<<G_ROW, B, 0, stream>>>(x, sLvec, sP, sGL);                               // p, gL

  // M backward -> gzM  (g2 -> R; g1 overwrites h1M in place: C==aux==P)
  k9bwd<<<G_EW, B, 0, stream>>>(sGL, MW3, Q, R);                                  // g2
  gemm_bf16<1><<<G_GEMM, B, 0, stream>>>(R, MW2tp, P, nullptr, P);                // g1 (in place)
  skinny6<<<G_SK, B, 0, stream>>>(P, MW1, sGzM);

  // G forward -> g_q
  l1fwd<<<G_EW, B, 0, stream>>>(x, GW1, Gb1, P);
  gemm_bf16<0><<<G_GEMM, B, 0, stream>>>(P, GW2p, R, Gb2, nullptr);
  skinny3<<<G_SK, B, 0, stream>>>(R, GW3, Gb3, sGq);

  // V backward -> gzV  (h1V in P; gv1 overwrites it in place)
  l1fwd<<<G_EW, B, 0, stream>>>(x, VW1, Vb1, P);                                  // vh1
  gemm_bf16<0><<<G_GEMM, B, 0, stream>>>(P, VW2p, R, Vb2, nullptr);               // vh2
  mapV<<<G_EW, B, 0, stream>>>(R, VW3);                                           // gv2
  gemm_bf16<1><<<G_GEMM, B, 0, stream>>>(R, VW2tp, P, nullptr, P);                // gv1 (in place)
  skinny6<<<G_SK, B, 0, stream>>>(P, VW1, sGzV);

  // assemble tangent, dp; write out[:, 0:6]
  rowB<<<G_ROW, B, 0, stream>>>(x, sGzM, sGzV, sGq, out, sDp);

  // JVP through M-net (aux = raw h2 in Q)
  l1t<<<G_EW, B, 0, stream>>>(x, out, MW1, Mb1, P);                               // th1
  gemm_bf16<1><<<G_GEMM, B, 0, stream>>>(P, MW2p, R, nullptr, Q);                 // th2
  skinny9<false><<<G_SK, B, 0, stream>>>(R, MW3, nullptr, sTL);                   // tLvec

  // final: ddq; write out[:, 6:10]
  rowC<<<G_ROW, B, 0, stream>>>(sLvec, sTL, sP, sDp, out);
}

// Round 16
// 912.208 us; speedup vs baseline: 1.5455x; 1.1192x over previous
//
#include <hip/hip_runtime.h>

// HNN structure embed (N=3, HID=1024, bs=32768).
// GEMMs: bf16 MFMA 16x16x32, 128x128x64 tiles, 2-slot LDS ring (64 KB),
// minimal 2-phase loop, __launch_bounds__(256,2), in-place EPI1 aliasing.
// R16 = R15 with the k9bwd grid fixed (16384 blocks, was 2048: rows 4096+
// were never computed -> absmax 126). Small kernels LDS-stage their tiny
// W matrices; mapV fused into V-forward GEMM as EPI2.
// Per-row 3x3 algebra in f32. dHdp == q_dot (exact). V layer-3 fwd skipped.

#define HID 1024
#define BS  32768

typedef __attribute__((ext_vector_type(8))) short short8;
typedef __attribute__((ext_vector_type(4))) float f32x4;
typedef __attribute__((ext_vector_type(8))) unsigned short ushort8v;
typedef __attribute__((ext_vector_type(4))) unsigned short ushort4v;

typedef __attribute__((address_space(1))) const char gconst_char;
typedef __attribute__((address_space(3))) char lds_char;

__device__ __forceinline__ unsigned short f2bf(float f) {
  unsigned int u = __builtin_bit_cast(unsigned int, f);
  u += 0x7fffu + ((u >> 16) & 1u);   // RNE
  return (unsigned short)(u >> 16);
}
__device__ __forceinline__ float bf2f(unsigned short s) {
  unsigned int u = ((unsigned int)s) << 16;
  return __builtin_bit_cast(float, u);
}
__device__ __forceinline__ float tanh_fast(float x) {
  float e = __builtin_amdgcn_exp2f(x * 2.885390081777927f); // e^(2x)
  return 1.f - 2.f * __builtin_amdgcn_rcpf(e + 1.f);
}

// ---------------- weight packing: pT[n][k]=bf16(W[k][n]); pC[n][k]=bf16(W[n][k])
__global__ __launch_bounds__(256) void pack_w(const float* __restrict__ W,
                                              unsigned short* __restrict__ pT,
                                              unsigned short* __restrict__ pC) {
  __shared__ float tile[64][65];
  int b = blockIdx.x;
  int k0 = (b >> 4) << 6;
  int n0 = (b & 15) << 6;
  int t = threadIdx.x;
  for (int i = 0; i < 16; ++i) {
    int idx = i * 256 + t;
    int r = idx >> 6, c = idx & 63;
    tile[r][c] = W[(size_t)(k0 + r) * HID + n0 + c];
  }
  if (pC) {
    for (int i = 0; i < 16; ++i) {
      int idx = i * 256 + t;
      int r = idx >> 6, c = idx & 63;
      pC[(size_t)(n0 + r) * HID + k0 + c] = f2bf(W[(size_t)(n0 + r) * HID + k0 + c]);
    }
  }
  __syncthreads();
  for (int i = 0; i < 16; ++i) {
    int idx = i * 256 + t;
    int n = idx >> 6, k = idx & 63;
    pT[(size_t)(n0 + n) * HID + k0 + k] = f2bf(tile[k][n]);
  }
}

// ---------------- big GEMM: C[m][n] = epi( sum_k A[m][k]*Bp[n][k] )
// EPI 0: tanh(acc + bias[col])
// EPI 1: acc * (1 - bf2f(aux[row][col])^2)  (aux = bf16 tanh act; may alias C)
// EPI 2: w3[col] * (1 - tanh(acc + bias[col])^2)   (fused mapV)
template<int EPI>
__global__ __launch_bounds__(256, 2) void gemm_bf16(
    const unsigned short* __restrict__ A,
    const unsigned short* __restrict__ Bp,
    unsigned short* __restrict__ C,
    const float* __restrict__ bias,
    const unsigned short* __restrict__ aux,
    const float* __restrict__ w3)
{
  __shared__ __align__(1024) char lds[65536];   // 2 x (A 16K + B 16K)
  const int t = threadIdx.x;
  const int w = t >> 6, l = t & 63;
  // bijective XCD swizzle: 2048 blocks, 8 XCDs -> each XCD owns 32 M-panels
  int bid = (int)blockIdx.x;
  int wg  = (bid & 7) * 256 + (bid >> 3);
  const int nt = wg & 7, mt = wg >> 3;
  const int r0 = mt << 7, n0 = nt << 7;
  const int wr = w >> 1, wc = w & 1;

  f32x4 acc[4][4] = {};
  const int lbase = (w << 2);

  const char* Abase = (const char*)A  + ((size_t)r0 << 11);
  const char* Bbase = (const char*)Bp + ((size_t)n0 << 11);

  // stage K-tile kt into slot with base `Ad`; lane offset recomputed inline
  auto STAGE = [&](char* Ad, int kt) {
    char* Bd = Ad + 16384;
    const char* Ak = Abase + kt * 128;
    const char* Bk = Bbase + kt * 128;
    #pragma unroll
    for (int i = 0; i < 4; ++i) {
      int o   = ((lbase + i) << 10) + (l << 4);
      int row = o >> 7;
      int vo  = (row << 11) + ((o & 127) ^ ((row & 7) << 4));   // inv swizzle on SOURCE
      __builtin_amdgcn_global_load_lds((gconst_char*)(Ak + vo), (lds_char*)(Ad + ((lbase + i) << 10)), 16, 0, 0);
      __builtin_amdgcn_global_load_lds((gconst_char*)(Bk + vo), (lds_char*)(Bd + ((lbase + i) << 10)), 16, 0, 0);
    }
  };

  auto COMPUTE = [&](const char* As) {
    const char* Bs = As + 16384;
    #pragma unroll
    for (int kk = 0; kk < 2; ++kk) {
      #pragma unroll
      for (int np = 0; np < 2; ++np) {
        int col = (wc << 6) + ((np << 1) << 4) + (l & 15);
        int boff = (col << 7) + ((l >> 4) << 4) + (kk << 6);
        boff ^= ((col & 7) << 4);
        short8 b0 = *(const short8*)(Bs + boff);
        short8 b1 = *(const short8*)(Bs + boff + 2048);   // col+16: XOR part unchanged
        #pragma unroll
        for (int m = 0; m < 4; ++m) {
          int row = (wr << 6) + (m << 4) + (l & 15);
          int aoff = (row << 7) + ((l >> 4) << 4) + (kk << 6);
          aoff ^= ((row & 7) << 4);
          short8 af = *(const short8*)(As + aoff);
          acc[m][(np << 1)]     = __builtin_amdgcn_mfma_f32_16x16x32_bf16(af, b0, acc[m][(np << 1)], 0, 0, 0);
          acc[m][(np << 1) + 1] = __builtin_amdgcn_mfma_f32_16x16x32_bf16(af, b1, acc[m][(np << 1) + 1], 0, 0, 0);
        }
        __builtin_amdgcn_sched_barrier(0);   // cap fragment live set per n-pair
      }
    }
  };

  char* L0 = lds;
  char* L1 = lds + 32768;

  // prologue: tile 0 into L0, drain, sync
  STAGE(L0, 0);
  asm volatile("s_waitcnt vmcnt(0)" ::: "memory");
  __builtin_amdgcn_s_barrier();

  // minimal 2-phase: STAGE(next) -> COMPUTE(cur) -> vmcnt(0) -> barrier.
  #pragma unroll 1
  for (int kt2 = 0; kt2 < 7; ++kt2) {
    STAGE(L1, 2 * kt2 + 1);
    COMPUTE(L0);
    asm volatile("s_waitcnt vmcnt(0)" ::: "memory");
    __builtin_amdgcn_s_barrier();
    STAGE(L0, 2 * kt2 + 2);
    COMPUTE(L1);
    asm volatile("s_waitcnt vmcnt(0)" ::: "memory");
    __builtin_amdgcn_s_barrier();
  }
  STAGE(L1, 15);
  COMPUTE(L0);
  asm volatile("s_waitcnt vmcnt(0)" ::: "memory");
  __builtin_amdgcn_s_barrier();
  COMPUTE(L1);
  __syncthreads();   // ds_reads retired before epilogue reuses LDS

  // epilogue: FULL unroll (compile-time acc indices -> AGPR, no scratch);
  // sched_barrier(0) after each m-chunk caps the accvgpr-read live range.
  char* Cs = lds;
  #pragma unroll
  for (int n = 0; n < 4; ++n) {
    const int colL = (wc << 6) + (n << 4) + (l & 15);
    const int gcol = n0 + colL;
    float bval = 0.f, w3v = 0.f;
    if (EPI == 0 || EPI == 2) bval = bias[gcol];
    if (EPI == 2) w3v = w3[gcol];
    #pragma unroll
    for (int m = 0; m < 4; ++m) {
      #pragma unroll
      for (int r = 0; r < 4; ++r) {
        const int rowL = (wr << 6) + (m << 4) + ((l >> 4) << 2) + r;
        float v = acc[m][n][r];
        if (EPI == 0) {
          v = tanh_fast(v + bval);
        } else if (EPI == 1) {
          float h = bf2f(aux[((size_t)(r0 + rowL) << 10) + gcol]);
          v *= (1.f - h * h);
        } else {
          float th = tanh_fast(v + bval);
          v = w3v * (1.f - th * th);
        }
        int so = (rowL << 8) + (colL << 1);
        so ^= ((rowL & 7) << 5);
        *(unsigned short*)(Cs + so) = f2bf(v);
      }
      __builtin_amdgcn_sched_barrier(0);   // cap live acc reads per chunk
    }
  }
  __syncthreads();   // all aux reads done; stores below (C may alias aux)
  #pragma unroll
  for (int j = 0; j < 8; ++j) {
    int o    = (j << 12) + (t << 4);
    int rowL = o >> 8;
    int ir   = o & 255;
    uint4 v = *(const uint4*)(Cs + ((rowL << 8) + (ir ^ ((rowL & 7) << 5))));
    *(uint4*)(C + ((size_t)(r0 + rowL) << 10) + n0 + (ir >> 1)) = v;
    __builtin_amdgcn_sched_barrier(0);  // cap store live set
  }
}

// ---------------- layer-1 forward: out = tanh(x6 @ W1 + b1), bf16
__global__ __launch_bounds__(256) void l1fwd(const float* __restrict__ x,
                                             const float* __restrict__ W1,
                                             const float* __restrict__ b1,
                                             unsigned short* __restrict__ out) {
  int idx = blockIdx.x * 256 + threadIdx.x;
  int r = idx >> 7;
  int n8 = (idx & 127) << 3;
  const float* xr = x + (size_t)r * 10;
  float xs[6];
  #pragma unroll
  for (int k = 0; k < 6; ++k) xs[k] = xr[k];
  float4 bb0 = *(const float4*)(b1 + n8), bb1 = *(const float4*)(b1 + n8 + 4);
  float z[8] = {bb0.x, bb0.y, bb0.z, bb0.w, bb1.x, bb1.y, bb1.z, bb1.w};
  #pragma unroll
  for (int k = 0; k < 6; ++k) {
    const float* wrow = W1 + (size_t)k * HID + n8;
    float4 wa = *(const float4*)wrow, wb = *(const float4*)(wrow + 4);
    z[0] += xs[k] * wa.x; z[1] += xs[k] * wa.y; z[2] += xs[k] * wa.z; z[3] += xs[k] * wa.w;
    z[4] += xs[k] * wb.x; z[5] += xs[k] * wb.y; z[6] += xs[k] * wb.z; z[7] += xs[k] * wb.w;
  }
  ushort8v o;
  #pragma unroll
  for (int j = 0; j < 8; ++j) o[j] = f2bf(tanh_fast(z[j]));
  *(ushort8v*)(out + (size_t)r * HID + n8) = o;
}

// ---------------- JVP layer-1: th1 = (tang @ W1) * (1 - tanh(x@W1+b1)^2)
__global__ __launch_bounds__(256) void l1t(const float* __restrict__ x,
                                           const float* __restrict__ outbuf, // tangent in cols 0..5
                                           const float* __restrict__ W1,
                                           const float* __restrict__ b1,
                                           unsigned short* __restrict__ P) {
  int idx = blockIdx.x * 256 + threadIdx.x;
  int r = idx >> 7;
  int n8 = (idx & 127) << 3;
  const float* xr = x + (size_t)r * 10;
  const float* tr = outbuf + (size_t)r * 10;
  float xs[6], ts[6];
  #pragma unroll
  for (int k = 0; k < 6; ++k) { xs[k] = xr[k]; ts[k] = tr[k]; }
  float4 bb0 = *(const float4*)(b1 + n8), bb1 = *(const float4*)(b1 + n8 + 4);
  float z[8] = {bb0.x, bb0.y, bb0.z, bb0.w, bb1.x, bb1.y, bb1.z, bb1.w};
  float tz[8] = {};
  #pragma unroll
  for (int k = 0; k < 6; ++k) {
    const float* wrow = W1 + (size_t)k * HID + n8;
    float4 wa = *(const float4*)wrow, wb = *(const float4*)(wrow + 4);
    z[0] += xs[k] * wa.x;  z[1] += xs[k] * wa.y;  z[2] += xs[k] * wa.z;  z[3] += xs[k] * wa.w;
    z[4] += xs[k] * wb.x;  z[5] += xs[k] * wb.y;  z[6] += xs[k] * wb.z;  z[7] += xs[k] * wb.w;
    tz[0] += ts[k] * wa.x; tz[1] += ts[k] * wa.y; tz[2] += ts[k] * wa.z; tz[3] += ts[k] * wa.w;
    tz[4] += ts[k] * wb.x; tz[5] += ts[k] * wb.y; tz[6] += ts[k] * wb.z; tz[7] += ts[k] * wb.w;
  }
  ushort8v o;
  #pragma unroll
  for (int j = 0; j < 8; ++j) {
    float th = tanh_fast(z[j]);
    o[j] = f2bf(tz[j] * (1.f - th * th));
  }
  *(ushort8v*)(P + (size_t)r * HID + n8) = o;
}

// ---------------- g2 = (gL @ MW3^T) * (1-h2^2), bf16  (K = 9, h2 raw)
// MW3 LDS-staged; spread-column mapping: lane-stride-9 LDS reads (no conflict)
__global__ __launch_bounds__(256) void k9bwd(const float* __restrict__ sGL,
                                             const float* __restrict__ MW3, // [1024][9]
                                             const unsigned short* __restrict__ h2,
                                             unsigned short* __restrict__ outp) {
  __shared__ float wsm[9216];
  int t = threadIdx.x;
  #pragma unroll
  for (int i = 0; i < 36; ++i) wsm[i * 256 + t] = MW3[i * 256 + t];
  __syncthreads();
  int idx = blockIdx.x * 256 + t;
  int r  = idx >> 7;
  int lc = idx & 127;
  const float* g = sGL + (size_t)r * 9;
  float gl[9];
  #pragma unroll
  for (int j = 0; j < 9; ++j) gl[j] = g[j];
  #pragma unroll
  for (int c = 0; c < 8; ++c) {
    int col = lc + (c << 7);
    const float* wr = wsm + col * 9;
    float s = 0.f;
    #pragma unroll
    for (int jj = 0; jj < 9; ++jj) s += gl[jj] * wr[jj];
    float h = bf2f(h2[(size_t)r * HID + col]);
    outp[(size_t)r * HID + col] = f2bf(s * (1.f - h * h));
  }
}

// ---------------- skinny reductions (wave per row)
// skinny9/skinny3 LDS-stage W ([1024][9]/[1024][3]): global gather -> LDS
// lane-stride-9/3 reads (conflict-free).
template<bool BIAS>
__global__ __launch_bounds__(256) void skinny9(const unsigned short* __restrict__ A,
                                               const float* __restrict__ W,  // [1024][9]
                                               const float* __restrict__ bias,
                                               float* __restrict__ out) {
  __shared__ float wsm[9216];
  {
    int t = threadIdx.x;
    #pragma unroll
    for (int i = 0; i < 36; ++i) wsm[i * 256 + t] = W[i * 256 + t];
  }
  __syncthreads();
  int wid = blockIdx.x * 4 + (threadIdx.x >> 6);
  int l = threadIdx.x & 63;
  const unsigned short* ar = A + (size_t)wid * HID;
  float acc[9] = {};
  for (int i = 0; i < 16; ++i) {
    int k = i * 64 + l;
    float a = bf2f(ar[k]);
    const float* wr = wsm + k * 9;
    #pragma unroll
    for (int j = 0; j < 9; ++j) acc[j] += a * wr[j];
  }
  #pragma unroll
  for (int j = 0; j < 9; ++j) {
    float sv = acc[j];
    for (int d = 32; d; d >>= 1) sv += __shfl_down(sv, d);
    if (l == 0) out[(size_t)wid * 9 + j] = BIAS ? (sv + bias[j]) : sv;
  }
}
__global__ __launch_bounds__(256) void skinny6(const unsigned short* __restrict__ A,
                                               const float* __restrict__ W,  // [6][1024]
                                               float* __restrict__ out) {
  int wid = blockIdx.x * 4 + (threadIdx.x >> 6);
  int l = threadIdx.x & 63;
  const unsigned short* ar = A + (size_t)wid * HID;
  float acc[6] = {};
  for (int i = 0; i < 4; ++i) {
    int k = i * 256 + l * 4;
    ushort4v av = *(const ushort4v*)(ar + k);
    float a0 = bf2f(av[0]), a1 = bf2f(av[1]), a2 = bf2f(av[2]), a3 = bf2f(av[3]);
    #pragma unroll
    for (int j = 0; j < 6; ++j) {
      float4 wv = *(const float4*)(W + (size_t)j * HID + k);
      acc[j] += a0 * wv.x + a1 * wv.y + a2 * wv.z + a3 * wv.w;
    }
  }
  #pragma unroll
  for (int j = 0; j < 6; ++j) {
    float sv = acc[j];
    for (int d = 32; d; d >>= 1) sv += __shfl_down(sv, d);
    if (l == 0) out[(size_t)wid * 6 + j] = sv;
  }
}
__global__ __launch_bounds__(256) void skinny3(const unsigned short* __restrict__ A,
                                               const float* __restrict__ W,  // [1024][3]
                                               const float* __restrict__ bias,
                                               float* __restrict__ out) {
  __shared__ float wsm[3072];
  {
    int t = threadIdx.x;
    #pragma unroll
    for (int i = 0; i < 12; ++i) wsm[i * 256 + t] = W[i * 256 + t];
  }
  __syncthreads();
  int wid = blockIdx.x * 4 + (threadIdx.x >> 6);
  int l = threadIdx.x & 63;
  const unsigned short* ar = A + (size_t)wid * HID;
  float a0 = 0.f, a1 = 0.f, a2 = 0.f;
  for (int i = 0; i < 16; ++i) {
    int k = i * 64 + l;
    float a = bf2f(ar[k]);
    const float* wr = wsm + k * 3;
    a0 += a * wr[0]; a1 += a * wr[1]; a2 += a * wr[2];
  }
  float acc[3] = {a0, a1, a2};
  #pragma unroll
  for (int j = 0; j < 3; ++j) {
    float sv = acc[j];
    for (int d = 32; d; d >>= 1) sv += __shfl_down(sv, d);
    if (l == 0) out[(size_t)wid * 3 + j] = sv + bias[j];
  }
}

// ---------------- per-row 3x3 algebra
__global__ __launch_bounds__(256) void rowA(const float* __restrict__ x,
                                            const float* __restrict__ sLvec,
                                            float* __restrict__ sP,
                                            float* __restrict__ sGL) {
  int r = blockIdx.x * 256 + threadIdx.x;
  const float* Lv = sLvec + (size_t)r * 9;
  float L[3][3];
  #pragma unroll
  for (int i = 0; i < 3; ++i)
    #pragma unroll
    for (int j = 0; j < 3; ++j) L[i][j] = Lv[3 * i + j];
  float a = 0.1f, b = 0.f, c = 0.f, d = 0.1f, e = 0.f, f = 0.1f;
  #pragma unroll
  for (int k = 0; k < 3; ++k) {
    a += L[0][k] * L[0][k]; b += L[0][k] * L[1][k]; c += L[0][k] * L[2][k];
    d += L[1][k] * L[1][k]; e += L[1][k] * L[2][k]; f += L[2][k] * L[2][k];
  }
  const float* xr = x + (size_t)r * 10;
  float q0 = xr[6], q1 = xr[7], q2 = xr[8];
  float c00 = d * f - e * e;
  float c01 = c * e - b * f;
  float c02 = b * e - c * d;
  float det = a * c00 + b * c01 + c * c02;
  float inv = 1.f / det;
  float i00 = c00 * inv, i01 = c01 * inv, i02 = c02 * inv;
  float i11 = (a * f - c * c) * inv;
  float i12 = (b * c - a * e) * inv;
  float i22 = (a * d - b * b) * inv;
  float p0 = i00 * q0 + i01 * q1 + i02 * q2;
  float p1 = i01 * q0 + i11 * q1 + i12 * q2;
  float p2 = i02 * q0 + i12 * q1 + i22 * q2;
  sP[(size_t)r * 3 + 0] = p0; sP[(size_t)r * 3 + 1] = p1; sP[(size_t)r * 3 + 2] = p2;
  float lt0 = p0 * L[0][0] + p1 * L[1][0] + p2 * L[2][0];
  float lt1 = p0 * L[0][1] + p1 * L[1][1] + p2 * L[2][1];
  float lt2 = p0 * L[0][2] + p1 * L[1][2] + p2 * L[2][2];
  float pp[3] = {p0, p1, p2}, lt[3] = {lt0, lt1, lt2};
  #pragma unroll
  for (int i = 0; i < 3; ++i)
    #pragma unroll
    for (int j = 0; j < 3; ++j) sGL[(size_t)r * 9 + 3 * i + j] = pp[i] * lt[j];
}

__global__ __launch_bounds__(256) void rowB(const float* __restrict__ x,
                                            const float* __restrict__ sGzM,
                                            const float* __restrict__ sGzV,
                                            const float* __restrict__ sGq,
                                            float* __restrict__ out,
                                            float* __restrict__ sDp) {
  int r = blockIdx.x * 256 + threadIdx.x;
  const float* xr = x + (size_t)r * 10;
  float u = xr[9];
  #pragma unroll
  for (int i = 0; i < 3; ++i) {
    float cosq = xr[i], sinq = xr[3 + i], qd = xr[6 + i];
    float dhc = sGzM[(size_t)r * 6 + i] + sGzV[(size_t)r * 6 + i];
    float dhs = sGzM[(size_t)r * 6 + 3 + i] + sGzV[(size_t)r * 6 + 3 + i];
    float F = sGq[(size_t)r * 3 + i] * u;
    float dq = qd;  // dHdp = M_inv @ p = q_dot exactly
    float dp = sinq * dhc - cosq * dhs + F;
    out[(size_t)r * 10 + i]     = -sinq * dq;
    out[(size_t)r * 10 + 3 + i] =  cosq * dq;
    sDp[(size_t)r * 3 + i] = dp;
  }
}

__global__ __launch_bounds__(256) void rowC(const float* __restrict__ sLvec,
                                            const float* __restrict__ sTL,
                                            const float* __restrict__ sP,
                                            const float* __restrict__ sDp,
                                            float* __restrict__ out) {
  int r = blockIdx.x * 256 + threadIdx.x;
  float L[3][3], T[3][3];
  #pragma unroll
  for (int i = 0; i < 3; ++i)
    #pragma unroll
    for (int j = 0; j < 3; ++j) {
      L[i][j] = sLvec[(size_t)r * 9 + 3 * i + j];
      T[i][j] = sTL[(size_t)r * 9 + 3 * i + j];
    }
  float Mi[3][3], dM[3][3];
  #pragma unroll
  for (int i = 0; i < 3; ++i) {
    #pragma unroll
    for (int j = 0; j < 3; ++j) {
      float s = 0.f, sd = 0.f;
      #pragma unroll
      for (int k = 0; k < 3; ++k) {
        s  += L[i][k] * L[j][k];
        sd += T[i][k] * L[j][k] + L[i][k] * T[j][k];
      }
      Mi[i][j] = s + (i == j ? 0.1f : 0.f);
      dM[i][j] = sd;
    }
  }
  float p[3], dp[3];
  #pragma unroll
  for (int i = 0; i < 3; ++i) { p[i] = sP[(size_t)r * 3 + i]; dp[i] = sDp[(size_t)r * 3 + i]; }
  #pragma unroll
  for (int i = 0; i < 3; ++i) {
    float s = 0.f;
    #pragma unroll
    for (int j = 0; j < 3; ++j) s += Mi[i][j] * dp[j] + dM[i][j] * p[j];
    out[(size_t)r * 10 + 6 + i] = s;
  }
  out[(size_t)r * 10 + 9] = 0.f;
}

// ---------------- host
extern "C" void kernel_launch(void* const* d_in, const int* in_sizes, int n_in,
                              void* d_out, int out_size, void* d_ws, size_t ws_size,
                              hipStream_t stream) {
  const float* x   = (const float*)d_in[1];
  const float* MW1 = (const float*)d_in[2];
  const float* Mb1 = (const float*)d_in[3];
  const float* MW2 = (const float*)d_in[4];
  const float* Mb2 = (const float*)d_in[5];
  const float* MW3 = (const float*)d_in[6];
  const float* Mb3 = (const float*)d_in[7];
  const float* VW1 = (const float*)d_in[8];
  const float* Vb1 = (const float*)d_in[9];
  const float* VW2 = (const float*)d_in[10];
  const float* Vb2 = (const float*)d_in[11];
  const float* VW3 = (const float*)d_in[12];
  const float* GW1 = (const float*)d_in[14];
  const float* Gb1 = (const float*)d_in[15];
  const float* GW2 = (const float*)d_in[16];
  const float* Gb2 = (const float*)d_in[17];
  const float* GW3 = (const float*)d_in[18];
  const float* Gb3 = (const float*)d_in[19];
  float* out = (float*)d_out;
  char* ws = (char*)d_ws;

  const size_t PK  = (size_t)HID * HID * 2;
  const size_t BUF = (size_t)BS * HID * 2;
  const size_t NEED = 5 * PK + 3 * BUF + (size_t)BS * 48 * 4;
  if (ws_size < NEED) return;  // ws too small: fail visibly (output untouched)

  unsigned short* MW2p  = (unsigned short*)(ws + 0 * PK);
  unsigned short* MW2tp = (unsigned short*)(ws + 1 * PK);
  unsigned short* VW2p  = (unsigned short*)(ws + 2 * PK);
  unsigned short* VW2tp = (unsigned short*)(ws + 3 * PK);
  unsigned short* GW2p  = (unsigned short*)(ws + 4 * PK);
  unsigned short* P = (unsigned short*)(ws + 5 * PK);
  unsigned short* Q = (unsigned short*)(ws + 5 * PK + BUF);
  unsigned short* R = (unsigned short*)(ws + 5 * PK + 2 * BUF);
  char* s = ws + 5 * PK + 3 * BUF;
  float* sLvec = (float*)(s);
  float* sP    = (float*)(s + (size_t)BS *  9 * 4);
  float* sGL   = (float*)(s + (size_t)BS * 12 * 4);
  float* sGzM  = (float*)(s + (size_t)BS * 21 * 4);
  float* sGzV  = (float*)(s + (size_t)BS * 27 * 4);
  float* sGq   = (float*)(s + (size_t)BS * 33 * 4);
  float* sDp   = (float*)(s + (size_t)BS * 36 * 4);
  float* sTL   = (float*)(s + (size_t)BS * 39 * 4);

  dim3 B(256);
  const int G_GEMM = 2048;          // 256 mt x 8 nt
  const int G_EW   = BS * 128 / 256; // 16384
  const int G_SK   = BS / 4;         // 8192
  const int G_ROW  = BS / 256;       // 128

  // weight packing
  pack_w<<<256, B, 0, stream>>>(MW2, MW2p, MW2tp);
  pack_w<<<256, B, 0, stream>>>(VW2, VW2p, VW2tp);
  pack_w<<<256, B, 0, stream>>>(GW2, GW2p, nullptr);

  // M forward (h1M stays in P until M-backward consumes it)
  l1fwd<<<G_EW, B, 0, stream>>>(x, MW1, Mb1, P);                                  // h1M
  gemm_bf16<0><<<G_GEMM, B, 0, stream>>>(P, MW2p, Q, Mb2, nullptr, nullptr);      // h2M (raw)
  skinny9<true><<<G_SK, B, 0, stream>>>(Q, MW3, Mb3, sLvec);                      // Lvec
  rowA<<<G_ROW, B, 0, stream>>>(x, sLvec, sP, sGL);                               // p, gL

  // M backward -> gzM  (g2 -> R; g1 overwrites h1M in place: C==aux==P)
  k9bwd<<<G_EW, B, 0, stream>>>(sGL, MW3, Q, R);                                  // g2
  gemm_bf16<1><<<G_GEMM, B, 0, stream>>>(R, MW2tp, P, nullptr, P, nullptr);       // g1 (in place)
  skinny6<<<G_SK, B, 0, stream>>>(P, MW1, sGzM);

  // G forward -> g_q
  l1fwd<<<G_EW, B, 0, stream>>>(x, GW1, Gb1, P);
  gemm_bf16<0><<<G_GEMM, B, 0, stream>>>(P, GW2p, R, Gb2, nullptr, nullptr);
  skinny3<<<G_SK, B, 0, stream>>>(R, GW3, Gb3, sGq);

  // V backward -> gzV  (h1V in P; EPI2 fuses mapV: R = gv2 directly)
  l1fwd<<<G_EW, B, 0, stream>>>(x, VW1, Vb1, P);                                  // vh1
  gemm_bf16<2><<<G_GEMM, B, 0, stream>>>(P, VW2p, R, Vb2, nullptr, VW3);          // gv2 (fused)
  gemm_bf16<1><<<G_GEMM, B, 0, stream>>>(R, VW2tp, P, nullptr, P, nullptr);       // gv1 (in place)
  skinny6<<<G_SK, B, 0, stream>>>(P, VW1, sGzV);

  // assemble tangent, dp; write out[:, 0:6]
  rowB<<<G_ROW, B, 0, stream>>>(x, sGzM, sGzV, sGq, out, sDp);

  // JVP through M-net (aux = raw h2 in Q)
  l1t<<<G_EW, B, 0, stream>>>(x, out, MW1, Mb1, P);                               // th1
  gemm_bf16<1><<<G_GEMM, B, 0, stream>>>(P, MW2p, R, nullptr, Q, nullptr);        // th2
  skinny9<false><<<G_SK, B, 0, stream>>>(R, MW3, nullptr, sTL);                   // tLvec

  // final: ddq; write out[:, 6:10]
  rowC<<<G_ROW, B, 0, stream>>>(sLvec, sTL, sP, sDp, out);
}